// Round 4
// baseline (306.266 us; speedup 1.0000x reference)
//
#include <hip/hip_runtime.h>
#include <math.h>

// B=8, C=3, H=1024, W=1024, N=512, D=256, PS=16, NB=8, NH=4, hd=64
// tokens M = B*N = 4096

typedef __attribute__((ext_vector_type(8))) short short8;
typedef __attribute__((ext_vector_type(4))) float floatx4;
typedef unsigned short u16;
typedef unsigned long long u64;

__device__ __forceinline__ float gelu_f(float x) {
  return 0.5f * x * (1.0f + erff(x * 0.70710678118654752f));
}

__device__ __forceinline__ u16 bf16_rn(float x) {
  union { float f; unsigned u; } v; v.f = x;
  unsigned r = v.u + 0x7fffu + ((v.u >> 16) & 1u);
  return (u16)(r >> 16);
}

__device__ __forceinline__ void split_bf16(float x, u16& h, u16& l) {
  h = bf16_rn(x);
  union { unsigned u; float f; } hv; hv.u = ((unsigned)h) << 16;
  l = bf16_rn(x - hv.f);
}

// weight segment offsets (elements)
#define W_PE   0
#define W_FE1  65536
#define W_FE2  67584
#define W_IN   100352
#define W_AO   296960
#define W_F1   362496
#define W_F2   493568
#define W_OP   624640

// ---------------------------------------------------------------------------
// Weights (except fe1) are stored FRAGMENT-MAJOR:
//   element (n,k) of an N x K matrix lives at
//   ((n>>4)*(K>>5) + (k>>5))*512 + (((k>>3)&3)*16 + (n&15))*8 + (k&7)
// ---------------------------------------------------------------------------

// mm16_swz: 16 rows x (4*NA*16) cols GEMM, bf16x3.  (4-wave blocks: k1)
template <int NA, int K>
__device__ __forceinline__ void mm16_swz(
    const u16* Ah, const u16* Al, const int S,
    const u16* __restrict__ Bh, const u16* __restrict__ Bl,
    floatx4* acc)
{
  const int t = threadIdx.x;
  const int w = t >> 6, lane = t & 63;
  const int lm = lane & 15, kg = lane >> 4;
  #pragma unroll
  for (int it = 0; it < K / 32; ++it) {
    const short8 a_h = *(const short8*)&Ah[lm * S + it * 32 + kg * 8];
    const short8 a_l = *(const short8*)&Al[lm * S + it * 32 + kg * 8];
    #pragma unroll
    for (int nj = 0; nj < NA; nj++) {
      const size_t wo = (size_t)(((w * NA + nj) * (K / 32) + it) * 512 + lane * 8);
      const short8 b_h = *(const short8*)&Bh[wo];
      const short8 b_l = *(const short8*)&Bl[wo];
      acc[nj] = __builtin_amdgcn_mfma_f32_16x16x32_bf16(a_h, b_h, acc[nj], 0, 0, 0);
      acc[nj] = __builtin_amdgcn_mfma_f32_16x16x32_bf16(a_h, b_l, acc[nj], 0, 0, 0);
      acc[nj] = __builtin_amdgcn_mfma_f32_16x16x32_bf16(a_l, b_h, acc[nj], 0, 0, 0);
    }
  }
}

// mm16_ks: same GEMM, K split NSETS ways across wave-sets (k2: 2, k4: 4).
template <int NA, int K, int NSETS>
__device__ __forceinline__ void mm16_ks(
    const u16* Ah, const u16* Al, const int S,
    const u16* __restrict__ Bh, const u16* __restrict__ Bl,
    floatx4* acc)
{
  const int t = threadIdx.x;
  const int w = t >> 6, lane = t & 63;
  const int ww = w & 3, set = w >> 2;
  const int lm = lane & 15, kg = lane >> 4;
  constexpr int ITERS = K / (32 * NSETS);
  #pragma unroll
  for (int itl = 0; itl < ITERS; ++itl) {
    const int it = set * ITERS + itl;
    const short8 a_h = *(const short8*)&Ah[lm * S + it * 32 + kg * 8];
    const short8 a_l = *(const short8*)&Al[lm * S + it * 32 + kg * 8];
    #pragma unroll
    for (int nj = 0; nj < NA; nj++) {
      const size_t wo = (size_t)(((ww * NA + nj) * (K / 32) + it) * 512 + lane * 8);
      const short8 b_h = *(const short8*)&Bh[wo];
      const short8 b_l = *(const short8*)&Bl[wo];
      acc[nj] = __builtin_amdgcn_mfma_f32_16x16x32_bf16(a_h, b_h, acc[nj], 0, 0, 0);
      acc[nj] = __builtin_amdgcn_mfma_f32_16x16x32_bf16(a_h, b_l, acc[nj], 0, 0, 0);
      acc[nj] = __builtin_amdgcn_mfma_f32_16x16x32_bf16(a_l, b_h, acc[nj], 0, 0, 0);
    }
  }
}

// reduce the 4 wave-set partials into set 0's acc (k4). PART rows stride 260.
template <int NA>
__device__ __forceinline__ void reduce_sets(floatx4* acc, float* PART)
{
  const int t = threadIdx.x;
  const int w = t >> 6, lane = t & 63;
  const int ww = w & 3, set = w >> 2;
  const int lm = lane & 15, kg = lane >> 4;
  __syncthreads();
  if (set != 0) {
    #pragma unroll
    for (int nj = 0; nj < NA; nj++) {
      const int col = ww * (NA * 16) + nj * 16 + lm;
      #pragma unroll
      for (int r = 0; r < 4; r++)
        PART[((set - 1) * 16 + kg * 4 + r) * 260 + col] = acc[nj][r];
    }
  }
  __syncthreads();
  if (set == 0) {
    #pragma unroll
    for (int nj = 0; nj < NA; nj++) {
      const int col = ww * (NA * 16) + nj * 16 + lm;
      #pragma unroll
      for (int r = 0; r < 4; r++) {
        const int rr = kg * 4 + r;
        acc[nj][r] += PART[rr * 260 + col] + PART[(16 + rr) * 260 + col]
                    + PART[(32 + rr) * 260 + col];
      }
    }
  }
}

// reduce 2 wave-set partials into set 0's acc (k2).
template <int NA>
__device__ __forceinline__ void reduce_sets2(floatx4* acc, float* PART)
{
  const int t = threadIdx.x;
  const int w = t >> 6, lane = t & 63;
  const int ww = w & 3, set = w >> 2;
  const int lm = lane & 15, kg = lane >> 4;
  __syncthreads();
  if (set == 1) {
    #pragma unroll
    for (int nj = 0; nj < NA; nj++) {
      const int col = ww * (NA * 16) + nj * 16 + lm;
      #pragma unroll
      for (int r = 0; r < 4; r++)
        PART[(kg * 4 + r) * 260 + col] = acc[nj][r];
    }
  }
  __syncthreads();
  if (set == 0) {
    #pragma unroll
    for (int nj = 0; nj < NA; nj++) {
      const int col = ww * (NA * 16) + nj * 16 + lm;
      #pragma unroll
      for (int r = 0; r < 4; r++)
        acc[nj][r] += PART[(kg * 4 + r) * 260 + col];
    }
  }
}

// coalesced global->LDS staging of a 16x256 u16 tile pair (stride 264), 256 thr
__device__ __forceinline__ void stage16(
    const u16* __restrict__ Gh, const u16* __restrict__ Gl,
    u16* Lh, u16* Ll)
{
  const int t = threadIdx.x;
  #pragma unroll
  for (int i = 0; i < 2; i++) {
    const int s = t + i * 256;
    const int row = s >> 5, c = (s & 31) * 8;
    *(short8*)&Lh[row * 264 + c] = *(const short8*)&Gh[(size_t)row * 256 + c];
    *(short8*)&Ll[row * 264 + c] = *(const short8*)&Gl[(size_t)row * 256 + c];
  }
  __syncthreads();
}

// per-row LayerNorm stats (4-wave blocks: k1)
template <int N_, int NA>
__device__ __forceinline__ void ln_rows(const float (&v)[NA][4], float* red1, float* red2,
                                        float (&mean)[4], float (&rstd)[4])
{
  const int t = threadIdx.x;
  const int w = t >> 6;
  const int lane = t & 63;
  const int kg = lane >> 4;
  float s1[4] = {0.f,0.f,0.f,0.f}, s2[4] = {0.f,0.f,0.f,0.f};
  #pragma unroll
  for (int nj = 0; nj < NA; nj++)
    #pragma unroll
    for (int r = 0; r < 4; r++) { s1[r] += v[nj][r]; s2[r] += v[nj][r] * v[nj][r]; }
  #pragma unroll
  for (int r = 0; r < 4; r++) {
    #pragma unroll
    for (int off = 1; off < 16; off <<= 1) {
      s1[r] += __shfl_xor(s1[r], off);
      s2[r] += __shfl_xor(s2[r], off);
    }
  }
  __syncthreads();
  if ((lane & 15) == 0) {
    #pragma unroll
    for (int r = 0; r < 4; r++) {
      red1[w * 16 + kg * 4 + r] = s1[r];
      red2[w * 16 + kg * 4 + r] = s2[r];
    }
  }
  __syncthreads();
  #pragma unroll
  for (int r = 0; r < 4; r++) {
    const int rw = kg * 4 + r;
    const float a = red1[rw] + red1[16 + rw] + red1[32 + rw] + red1[48 + rw];
    const float b = red2[rw] + red2[16 + rw] + red2[32 + rw] + red2[48 + rw];
    mean[r] = a * (1.0f / N_);
    rstd[r] = rsqrtf(b * (1.0f / N_) - mean[r] * mean[r] + 1e-5f);
  }
}

// LN for 16-wave split-K blocks (k4); only set 0's stats count.
template <int N_, int NA>
__device__ __forceinline__ void ln_rows16(const float (&v)[NA][4], float* red1, float* red2,
                                          float (&mean)[4], float (&rstd)[4])
{
  const int t = threadIdx.x;
  const int w = t >> 6;
  const int lane = t & 63;
  const int ww = w & 3, set = w >> 2;
  const int kg = lane >> 4;
  float s1[4] = {0.f,0.f,0.f,0.f}, s2[4] = {0.f,0.f,0.f,0.f};
  #pragma unroll
  for (int nj = 0; nj < NA; nj++)
    #pragma unroll
    for (int r = 0; r < 4; r++) { s1[r] += v[nj][r]; s2[r] += v[nj][r] * v[nj][r]; }
  #pragma unroll
  for (int r = 0; r < 4; r++) {
    #pragma unroll
    for (int off = 1; off < 16; off <<= 1) {
      s1[r] += __shfl_xor(s1[r], off);
      s2[r] += __shfl_xor(s2[r], off);
    }
  }
  __syncthreads();
  if (set == 0 && (lane & 15) == 0) {
    #pragma unroll
    for (int r = 0; r < 4; r++) {
      red1[ww * 16 + kg * 4 + r] = s1[r];
      red2[ww * 16 + kg * 4 + r] = s2[r];
    }
  }
  __syncthreads();
  if (set == 0) {
    #pragma unroll
    for (int r = 0; r < 4; r++) {
      const int rw = kg * 4 + r;
      const float a = red1[rw] + red1[16 + rw] + red1[32 + rw] + red1[48 + rw];
      const float b = red2[rw] + red2[16 + rw] + red2[32 + rw] + red2[48 + rw];
      mean[r] = a * (1.0f / N_);
      rstd[r] = rsqrtf(b * (1.0f / N_) - mean[r] * mean[r] + 1e-5f);
    }
  }
}

// store 4 consecutive (same-n) elements into fragment-major layout
__device__ __forceinline__ void store_swz(
    u16* __restrict__ Wh, u16* __restrict__ Wl, const int segbase,
    const int rel, const int kshift, const float4 v)
{
  const int K = 1 << kshift;
  const int n = rel >> kshift;
  const int k = rel & (K - 1);
  const int off8 = ((n >> 4) * (K >> 5) + (k >> 5)) * 512
                 + (((k >> 3) & 3) * 16 + (n & 15)) * 8 + (k & 7);
  u16 h0,h1,h2,h3,l0,l1,l2,l3;
  split_bf16(v.x,h0,l0); split_bf16(v.y,h1,l1);
  split_bf16(v.z,h2,l2); split_bf16(v.w,h3,l3);
  *(u64*)&Wh[segbase + off8] = (u64)h0 | ((u64)h1<<16) | ((u64)h2<<32) | ((u64)h3<<48);
  *(u64*)&Wl[segbase + off8] = (u64)l0 | ((u64)l1<<16) | ((u64)l2<<32) | ((u64)l3<<48);
}

// ---------------------------------------------------------------------------
// K0: weight split+swizzle (blocks 0..2695) + featurize (2696..6791), 64 thr
// ---------------------------------------------------------------------------
__global__ __launch_bounds__(64) void k0_prep(
    const float* __restrict__ image, const float* __restrict__ coords,
    const float* __restrict__ fbi,
    const float* __restrict__ pe_w, const float* __restrict__ fe1_w,
    const float* __restrict__ fe2_w, const float* __restrict__ in_w,
    const float* __restrict__ ao_w, const float* __restrict__ f1_w,
    const float* __restrict__ f2_w, const float* __restrict__ op_w,
    u16* __restrict__ Wh, u16* __restrict__ Wl,
    u16* __restrict__ PEh, u16* __restrict__ PEl,
    u16* __restrict__ FEATh, u16* __restrict__ FEATl)
{
  const int blk = blockIdx.x;
  const int lane = threadIdx.x;

  if (blk < 2696) {
    const int idx = (blk * 64 + lane) * 4;
    if (idx < W_FE1) {
      store_swz(Wh, Wl, W_PE, idx - W_PE, 8, *(const float4*)&pe_w[idx - W_PE]);
    } else if (idx < W_FE2) {
      const int rel = idx - W_FE1;
      const float4 v = *(const float4*)&fe1_w[rel];
      u16 h0,h1,h2,h3,l0,l1,l2,l3;
      split_bf16(v.x,h0,l0); split_bf16(v.y,h1,l1);
      split_bf16(v.z,h2,l2); split_bf16(v.w,h3,l3);
      *(u64*)&Wh[idx] = (u64)h0 | ((u64)h1<<16) | ((u64)h2<<32) | ((u64)h3<<48);
      *(u64*)&Wl[idx] = (u64)l0 | ((u64)l1<<16) | ((u64)l2<<32) | ((u64)l3<<48);
    } else if (idx < W_IN) {
      store_swz(Wh, Wl, W_FE2, idx - W_FE2, 7, *(const float4*)&fe2_w[idx - W_FE2]);
    } else if (idx < W_AO) {
      store_swz(Wh, Wl, W_IN, idx - W_IN, 8, *(const float4*)&in_w[idx - W_IN]);
    } else if (idx < W_F1) {
      store_swz(Wh, Wl, W_AO, idx - W_AO, 8, *(const float4*)&ao_w[idx - W_AO]);
    } else if (idx < W_F2) {
      store_swz(Wh, Wl, W_F1, idx - W_F1, 8, *(const float4*)&f1_w[idx - W_F1]);
    } else if (idx < W_OP) {
      store_swz(Wh, Wl, W_F2, idx - W_F2, 9, *(const float4*)&f2_w[idx - W_F2]);
    } else {
      store_swz(Wh, Wl, W_OP, idx - W_OP, 8, *(const float4*)&op_w[idx - W_OP]);
    }
    return;
  }

  const int id = blk - 2696;
  const int b  = id >> 9;
  const float pcx = coords[id * 2 + 0];
  const float pcy = coords[id * 2 + 1];

  {
    const float TWO_PI = 6.283185307179586f;
    const float dimt = expf((float)lane * 0.28782313662425572f); // ln(1e4)/32
    const float ax = (pcx * (1.0f / 1024.0f)) * TWO_PI / dimt;
    const float ay = (pcy * (1.0f / 1024.0f)) * TWO_PI / dimt;
    u16 h, l;
    split_bf16(sinf(ax), h, l); PEh[id*256+lane]     = h; PEl[id*256+lane]     = l;
    split_bf16(cosf(ax), h, l); PEh[id*256+lane+64]  = h; PEl[id*256+lane+64]  = l;
    split_bf16(sinf(ay), h, l); PEh[id*256+lane+128] = h; PEl[id*256+lane+128] = l;
    split_bf16(cosf(ay), h, l); PEh[id*256+lane+192] = h; PEl[id*256+lane+192] = l;
  }

  int px = (int)pcx; px = px < 8 ? 8 : (px > 1015 ? 1015 : px);
  int py = (int)pcy; py = py < 8 ? 8 : (py > 1015 ? 1015 : py);

  __shared__ float patch[256];
  __shared__ float ct[16], st[16];
  __shared__ float Gre[144], Gim[144];
  __shared__ float msum[8], psum[8];
  __shared__ int cnt8[8];
  {
    const float* img = image + (size_t)b * 3145728;
    #pragma unroll
    for (int i = 0; i < 4; i++) {
      const int p = i * 64 + lane;
      const int r = p >> 4, c = p & 15;
      const int off = (py - 8 + r) * 1024 + (px - 8 + c);
      const float s = img[off] + img[off + 1048576] + img[off + 2097152];
      patch[r * 16 + c] = s * (1.0f / 3.0f);
    }
  }
  if (lane < 16) {
    float c, s;
    if ((lane & 3) == 0) {
      const float cv[4] = {1.0f, 0.0f, -1.0f, 0.0f};
      const float sv[4] = {0.0f, -1.0f, 0.0f, 1.0f};
      c = cv[lane >> 2]; s = sv[lane >> 2];
    } else {
      const float a = -3.14159265358979f * (float)lane * 0.125f;
      c = cosf(a); s = sinf(a);
    }
    ct[lane] = c; st[lane] = s;
  }
  if (lane < 8) { msum[lane] = 0.0f; psum[lane] = 0.0f; cnt8[lane] = 0; }
  __syncthreads();

  for (int tt = lane; tt < 144; tt += 64) {
    const int y = tt / 9, kx = tt - y * 9;
    float re = 0.0f, im = 0.0f;
    #pragma unroll
    for (int x = 0; x < 16; x++) {
      const int w = (x * kx) & 15;
      const float pv = patch[y * 16 + x];
      re = fmaf(pv, ct[w], re);
      im = fmaf(pv, st[w], im);
    }
    Gre[tt] = re; Gim[tt] = im;
  }
  __syncthreads();

  for (int tt = lane; tt < 144; tt += 64) {
    const int ky = tt / 9, kx = tt - ky * 9;
    float re = 0.0f, im = 0.0f;
    #pragma unroll
    for (int y = 0; y < 16; y++) {
      const int w = (y * ky) & 15;
      const float gr = Gre[y * 9 + kx], gi = Gim[y * 9 + kx];
      re = fmaf(gr, ct[w], re);
      re = fmaf(-gi, st[w], re);
      im = fmaf(gr, st[w], im);
      im = fmaf(gi, ct[w], im);
    }
    if (((ky & 7) == 0) && ((kx & 7) == 0)) im = 0.0f;
    const float mag = sqrtf(re * re + im * im) * 0.0625f;
    const float ph  = atan2f(im, re);

    const float fy = (ky < 8) ? (float)ky * 0.0625f : (float)(ky - 16) * 0.0625f;
    const float fx = (float)kx * 0.0625f;
    const float r = sqrtf(fx * fx + fy * fy);
    const float max_r = 0.7071077811865476f;
    const float stepf = max_r * 0.125f;
    int idx = 0;
    #pragma unroll
    for (int kq = 1; kq <= 8; kq++) {
      const float e = (kq == 8) ? max_r : stepf * (float)kq;
      if (r >= e) idx = kq;
    }
    if (idx > 7) idx = 7;
    atomicAdd(&msum[idx], mag);
    atomicAdd(&psum[idx], ph);
    atomicAdd(&cnt8[idx], 1);
  }
  __syncthreads();

  if (lane < 8) {
    float fm = fbi[0];
    #pragma unroll
    for (int j = 1; j < 8; j++) fm = fmaxf(fm, fbi[j]);
    float se = 0.0f;
    #pragma unroll
    for (int j = 0; j < 8; j++) se += expf(fbi[j] - fm);
    const float smx = expf(fbi[lane] - fm) / se;
    const float c = (float)(cnt8[lane] > 0 ? cnt8[lane] : 1);
    u16 h, l;
    split_bf16((msum[lane] / c) * smx, h, l);
    FEATh[id*16+lane] = h; FEATl[id*16+lane] = l;
    split_bf16(psum[lane] / c, h, l);
    FEATh[id*16+8+lane] = h; FEATl[id*16+8+lane] = l;
  }
}

// ---------------------------------------------------------------------------
// K1: blocks 0..255 spatial (staged A, swz B); 256..511 freq-MLP  (unchanged)
// ---------------------------------------------------------------------------
__global__ __launch_bounds__(256) void k1_front(
    const u16* __restrict__ Wh, const u16* __restrict__ Wl,
    const u16* __restrict__ PEh, const u16* __restrict__ PEl,
    const u16* __restrict__ FEATh, const u16* __restrict__ FEATl,
    const float* __restrict__ pe_b, const int* __restrict__ labels,
    const float* __restrict__ temb,
    const float* __restrict__ fe1_b, const float* __restrict__ feln1_g, const float* __restrict__ feln1_b,
    const float* __restrict__ fe2_b, const float* __restrict__ feln2_g, const float* __restrict__ feln2_b,
    float* __restrict__ SPATIAL32, u16* __restrict__ SPh, u16* __restrict__ SPl,
    u16* __restrict__ FQh, u16* __restrict__ FQl)
{
  __shared__ __align__(16) u16 smem[8448];
  __shared__ float redbuf[128];
  const int blk = blockIdx.x;
  const int t = threadIdx.x;
  const int w = t >> 6, lane = t & 63;
  const int lm = lane & 15, kg = lane >> 4;

  if (blk < 256) {
    const int m0 = blk * 16;
    u16* Lh = smem;          // 16 x 264
    u16* Ll = smem + 4224;
    stage16(PEh + (size_t)m0 * 256, PEl + (size_t)m0 * 256, Lh, Ll);
    floatx4 acc[4];
    #pragma unroll
    for (int j = 0; j < 4; j++) acc[j] = (floatx4){0.f,0.f,0.f,0.f};
    mm16_swz<4, 256>(Lh, Ll, 264, Wh + W_PE, Wl + W_PE, acc);
    #pragma unroll
    for (int nj = 0; nj < 4; nj++) {
      const int col = w * 64 + nj * 16 + lm;
      #pragma unroll
      for (int r = 0; r < 4; r++) {
        const int row = m0 + kg * 4 + r;
        const float v = acc[nj][r] + pe_b[col] + temb[labels[row] * 256 + col];
        SPATIAL32[(size_t)row * 256 + col] = v;
        u16 h, l; split_bf16(v, h, l);
        SPh[(size_t)row * 256 + col] = h;
        SPl[(size_t)row * 256 + col] = l;
      }
    }
    return;
  }

  const int m0 = (blk - 256) * 16;
  u16* h1h = smem;           // 16 x 136
  u16* h1l = smem + 2176;

  floatx4 acc1[2];
  acc1[0] = (floatx4){0.f,0.f,0.f,0.f};
  acc1[1] = (floatx4){0.f,0.f,0.f,0.f};
  {
    const short8 zz = {0,0,0,0,0,0,0,0};
    const short8 a_h = (kg < 2) ? *(const short8*)&FEATh[(size_t)(m0 + lm) * 16 + kg * 8] : zz;
    const short8 a_l = (kg < 2) ? *(const short8*)&FEATl[(size_t)(m0 + lm) * 16 + kg * 8] : zz;
    #pragma unroll
    for (int nj = 0; nj < 2; nj++) {
      const int col = w * 32 + nj * 16 + lm;
      const short8 b_h = (kg < 2) ? *(const short8*)&Wh[W_FE1 + (size_t)col * 16 + kg * 8] : zz;
      const short8 b_l = (kg < 2) ? *(const short8*)&Wl[W_FE1 + (size_t)col * 16 + kg * 8] : zz;
      acc1[nj] = __builtin_amdgcn_mfma_f32_16x16x32_bf16(a_h, b_h, acc1[nj], 0, 0, 0);
      acc1[nj] = __builtin_amdgcn_mfma_f32_16x16x32_bf16(a_h, b_l, acc1[nj], 0, 0, 0);
      acc1[nj] = __builtin_amdgcn_mfma_f32_16x16x32_bf16(a_l, b_h, acc1[nj], 0, 0, 0);
    }
  }

  float v1[2][4];
  #pragma unroll
  for (int nj = 0; nj < 2; nj++) {
    const int col = w * 32 + nj * 16 + lm;
    #pragma unroll
    for (int r = 0; r < 4; r++) v1[nj][r] = acc1[nj][r] + fe1_b[col];
  }
  float mean[4], rstd[4];
  ln_rows<128, 2>(v1, redbuf, redbuf + 64, mean, rstd);
  #pragma unroll
  for (int nj = 0; nj < 2; nj++) {
    const int col = w * 32 + nj * 16 + lm;
    #pragma unroll
    for (int r = 0; r < 4; r++) {
      float y = feln1_g[col] * (v1[nj][r] - mean[r]) * rstd[r] + feln1_b[col];
      y = gelu_f(y);
      u16 h, l; split_bf16(y, h, l);
      h1h[(kg * 4 + r) * 136 + col] = h;
      h1l[(kg * 4 + r) * 136 + col] = l;
    }
  }
  __syncthreads();

  floatx4 acc2[4];
  #pragma unroll
  for (int j = 0; j < 4; j++) acc2[j] = (floatx4){0.f,0.f,0.f,0.f};
  mm16_swz<4, 128>(h1h, h1l, 136, Wh + W_FE2, Wl + W_FE2, acc2);

  float v2[4][4];
  #pragma unroll
  for (int nj = 0; nj < 4; nj++) {
    const int col = w * 64 + nj * 16 + lm;
    #pragma unroll
    for (int r = 0; r < 4; r++) v2[nj][r] = acc2[nj][r] + fe2_b[col];
  }
  ln_rows<256, 4>(v2, redbuf, redbuf + 64, mean, rstd);
  #pragma unroll
  for (int nj = 0; nj < 4; nj++) {
    const int col = w * 64 + nj * 16 + lm;
    #pragma unroll
    for (int r = 0; r < 4; r++) {
      const int rw = m0 + kg * 4 + r;
      float y = feln2_g[col] * (v2[nj][r] - mean[r]) * rstd[r] + feln2_b[col];
      u16 h, l; split_bf16(y, h, l);
      FQh[(size_t)rw * 256 + col] = h;
      FQl[(size_t)rw * 256 + col] = l;
    }
  }
}

// ---------------------------------------------------------------------------
// K2: QKV projection, 512 threads, split-K-2: set 0 = K[0,128), set 1 = K[128,256).
// Set 1 dumps partials to PART; set 0 reduces + epilogue. Occupancy 3->6 waves/SIMD.
// ---------------------------------------------------------------------------
__global__ __launch_bounds__(512) void k2_qkv(
    const u16* __restrict__ Wh, const u16* __restrict__ Wl,
    const u16* __restrict__ SPh, const u16* __restrict__ SPl,
    const u16* __restrict__ FQh, const u16* __restrict__ FQl,
    const float* __restrict__ in_b,
    u16* __restrict__ Qh, u16* __restrict__ Ql,
    u16* __restrict__ Kh, u16* __restrict__ Kl,
    u16* __restrict__ Vth, u16* __restrict__ Vtl)
{
  __shared__ __align__(16) u16 smem[8448];
  __shared__ float PART[16 * 260];
  const int bx = blockIdx.x;
  const int seg = bx >> 8;
  const int m0 = (bx & 255) * 16;
  const int t = threadIdx.x;
  const int w = t >> 6, lane = t & 63;
  const int ww = w & 3, set = w >> 2;
  const int lm = lane & 15, kg = lane >> 4;

  const u16 *Ah, *Al; const u16 *Wsh, *Wsl; const float* bias;
  if (seg == 0)      { Ah = SPh; Al = SPl; Wsh = Wh + W_IN;          Wsl = Wl + W_IN;          bias = in_b; }
  else if (seg == 1) { Ah = FQh; Al = FQl; Wsh = Wh + W_IN + 65536;  Wsl = Wl + W_IN + 65536;  bias = in_b + 256; }
  else               { Ah = FQh; Al = FQl; Wsh = Wh + W_IN + 131072; Wsl = Wl + W_IN + 131072; bias = in_b + 512; }

  u16* Lh = smem;
  u16* Ll = smem + 4224;
  // stage 16x256 tile with 512 threads in one pass
  {
    const u16* Gh = Ah + (size_t)m0 * 256;
    const u16* Gl = Al + (size_t)m0 * 256;
    const int row = t >> 5, c = (t & 31) * 8;
    *(short8*)&Lh[row * 264 + c] = *(const short8*)&Gh[(size_t)row * 256 + c];
    *(short8*)&Ll[row * 264 + c] = *(const short8*)&Gl[(size_t)row * 256 + c];
    __syncthreads();
  }

  floatx4 acc[4];
  #pragma unroll
  for (int j = 0; j < 4; j++) acc[j] = (floatx4){0.f,0.f,0.f,0.f};
  mm16_ks<4, 256, 2>(Lh, Ll, 264, Wsh, Wsl, acc);
  reduce_sets2<4>(acc, PART);

  if (set != 0) return;

  if (seg < 2) {
    u16* oh = (seg == 0) ? Qh : Kh;
    u16* ol = (seg == 0) ? Ql : Kl;
    #pragma unroll
    for (int nj = 0; nj < 4; nj++) {
      const int col = ww * 64 + nj * 16 + lm;
      #pragma unroll
      for (int r = 0; r < 4; r++) {
        const int row = m0 + kg * 4 + r;
        u16 h, l; split_bf16(acc[nj][r] + bias[col], h, l);
        oh[(size_t)row * 256 + col] = h;
        ol[(size_t)row * 256 + col] = l;
      }
    }
  } else {
    #pragma unroll
    for (int nj = 0; nj < 4; nj++) {
      const int col = ww * 64 + nj * 16 + lm;
      u64 hp = 0, lp = 0;
      #pragma unroll
      for (int r = 0; r < 4; r++) {
        u16 h, l; split_bf16(acc[nj][r] + bias[col], h, l);
        hp |= ((u64)h) << (16 * r);
        lp |= ((u64)l) << (16 * r);
      }
      *(u64*)&Vth[(size_t)col * 4096 + m0 + kg * 4] = hp;
      *(u64*)&Vtl[(size_t)col * 4096 + m0 + kg * 4] = lp;
    }
  }
}

// ---------------------------------------------------------------------------
// K3: flash attention, 512 blocks x 256 thr. Block (bh,qt,half) handles
// kt = half*4 .. half*4+3 and writes UNNORMALIZED f32 partial O + (m,l).
// The two-partial merge happens in k4's staging step.
// ---------------------------------------------------------------------------
__global__ __launch_bounds__(256) void k3_attn(
    const u16* __restrict__ Qh, const u16* __restrict__ Ql,
    const u16* __restrict__ Kh, const u16* __restrict__ Kl,
    const u16* __restrict__ Vth, const u16* __restrict__ Vtl,
    float* __restrict__ OP, float* __restrict__ ML)
{
  __shared__ __align__(16) u16 smem[36864];   // 73728 B -> 2 blocks/CU
  u16* sQh = smem;          // 64 x 72
  u16* sQl = smem + 4608;
  u16* sKh = smem + 9216;
  u16* sKl = smem + 13824;
  u16* sVh = smem + 18432;
  u16* sVl = smem + 23040;
  u16* sPh = smem + 27648;
  u16* sPl = smem + 32256;

  const int bx = blockIdx.x;
  const int half = bx & 1;
  const int qt = (bx >> 1) & 7;
  const int bh = bx >> 4;
  const int b = bh >> 2, h = bh & 3;
  const int t = threadIdx.x;
  const int w = t >> 6, lane = t & 63;
  const int lm = lane & 15, kg = lane >> 4;
  const int qrow0 = b * 512 + qt * 64;

  #pragma unroll
  for (int i = 0; i < 2; i++) {
    const int s = t + i * 256;
    const int r = s >> 3, d = (s & 7) * 8;
    *(short8*)&sQh[r * 72 + d] = *(const short8*)&Qh[(size_t)(qrow0 + r) * 256 + h * 64 + d];
    *(short8*)&sQl[r * 72 + d] = *(const short8*)&Ql[(size_t)(qrow0 + r) * 256 + h * 64 + d];
  }

  float m_i[4], l_i[4];
  floatx4 o_acc[4];
  #pragma unroll
  for (int r = 0; r < 4; r++) { m_i[r] = -INFINITY; l_i[r] = 0.0f; }
  #pragma unroll
  for (int dj = 0; dj < 4; dj++) o_acc[dj] = (floatx4){0.f, 0.f, 0.f, 0.f};

  __syncthreads();
  short8 q_h[2], q_l[2];
  #pragma unroll
  for (int ks = 0; ks < 2; ks++) {
    const int off = (w * 16 + lm) * 72 + ks * 32 + kg * 8;
    q_h[ks] = *(const short8*)&sQh[off];
    q_l[ks] = *(const short8*)&sQl[off];
  }

  for (int ktl = 0; ktl < 4; ktl++) {
    const int kt = half * 4 + ktl;
    __syncthreads();
    {
      const int krow0 = b * 512 + kt * 64;
      #pragma unroll
      for (int i = 0; i < 2; i++) {
        const int s = t + i * 256;
        const int r = s >> 3, d = (s & 7) * 8;
        *(short8*)&sKh[r * 72 + d] = *(const short8*)&Kh[(size_t)(krow0 + r) * 256 + h * 64 + d];
        *(short8*)&sKl[r * 72 + d] = *(const short8*)&Kl[(size_t)(krow0 + r) * 256 + h * 64 + d];
        *(short8*)&sVh[r * 72 + d] = *(const short8*)&Vth[(size_t)(h * 64 + r) * 4096 + krow0 + d];
        *(short8*)&sVl[r * 72 + d] = *(const short8*)&Vtl[(size_t)(h * 64 + r) * 4096 + krow0 + d];
      }
    }
    __syncthreads();

    floatx4 sacc[4];
    #pragma unroll
    for (int nj = 0; nj < 4; nj++) sacc[nj] = (floatx4){0.f, 0.f, 0.f, 0.f};
    #pragma unroll
    for (int ks = 0; ks < 2; ks++) {
      #pragma unroll
      for (int nj = 0; nj < 4; nj++) {
        const int off = (nj * 16 + lm) * 72 + ks * 32 + kg * 8;
        const short8 kb_h = *(const short8*)&sKh[off];
        const short8 kb_l = *(const short8*)&sKl[off];
        sacc[nj] = __builtin_amdgcn_mfma_f32_16x16x32_bf16(q_h[ks], kb_h, sacc[nj], 0, 0, 0);
        sacc[nj] = __builtin_amdgcn_mfma_f32_16x16x32_bf16(q_h[ks], kb_l, sacc[nj], 0, 0, 0);
        sacc[nj] = __builtin_amdgcn_mfma_f32_16x16x32_bf16(q_l[ks], kb_h, sacc[nj], 0, 0, 0);
      }
    }

    float pp[4][4];
    #pragma unroll
    for (int r = 0; r < 4; r++) {
      float mx = -INFINITY;
      #pragma unroll
      for (int nj = 0; nj < 4; nj++) {
        sacc[nj][r] *= 0.125f;
        mx = fmaxf(mx, sacc[nj][r]);
      }
      #pragma unroll
      for (int off = 1; off < 16; off <<= 1) mx = fmaxf(mx, __shfl_xor(mx, off));
      const float mnew = fmaxf(m_i[r], mx);
      const float alpha = expf(m_i[r] - mnew);
      m_i[r] = mnew;
      float rs = 0.0f;
      #pragma unroll
      for (int nj = 0; nj < 4; nj++) { pp[nj][r] = expf(sacc[nj][r] - mnew); rs += pp[nj][r]; }
      #pragma unroll
      for (int off = 1; off < 16; off <<= 1) rs += __shfl_xor(rs, off);
      l_i[r] = l_i[r] * alpha + rs;
      #pragma unroll
      for (int dj = 0; dj < 4; dj++) o_acc[dj][r] *= alpha;
    }

    #pragma unroll
    for (int nj = 0; nj < 4; nj++)
      #pragma unroll
      for (int r = 0; r < 4; r++) {
        u16 ph, pl; split_bf16(pp[nj][r], ph, pl);
        sPh[(w * 16 + kg * 4 + r) * 72 + nj * 16 + lm] = ph;
        sPl[(w * 16 + kg * 4 + r) * 72 + nj * 16 + lm] = pl;
      }

    #pragma unroll
    for (int ks = 0; ks < 2; ks++) {
      const short8 p_h = *(const short8*)&sPh[(w * 16 + lm) * 72 + ks * 32 + kg * 8];
      const short8 p_l = *(const short8*)&sPl[(w * 16 + lm) * 72 + ks * 32 + kg * 8];
      #pragma unroll
      for (int dj = 0; dj < 4; dj++) {
        const int off = (dj * 16 + lm) * 72 + ks * 32 + kg * 8;
        const short8 v_h = *(const short8*)&sVh[off];
        const short8 v_l = *(const short8*)&sVl[off];
        o_acc[dj] = __builtin_amdgcn_mfma_f32_16x16x32_bf16(p_h, v_h, o_acc[dj], 0, 0, 0);
        o_acc[dj] = __builtin_amdgcn_mfma_f32_16x16x32_bf16(p_l, v_h, o_acc[dj], 0, 0, 0);
        o_acc[dj] = __builtin_amdgcn_mfma_f32_16x16x32_bf16(p_h, v_l, o_acc[dj], 0, 0, 0);
      }
    }
  }

  // store unnormalized partial O (f32) + per-(row,head) m,l
  #pragma unroll
  for (int r = 0; r < 4; r++) {
    const int row = w * 16 + kg * 4 + r;
    const int grow = qrow0 + row;
    if (lm == 0) {
      ML[half * 32768 + grow * 8 + h * 2]     = m_i[r];
      ML[half * 32768 + grow * 8 + h * 2 + 1] = l_i[r];
    }
    #pragma unroll
    for (int dj = 0; dj < 4; dj++)
      OP[(size_t)half * 1048576 + (size_t)grow * 256 + h * 64 + dj * 16 + lm] = o_acc[dj][r];
  }
}

// ---------------------------------------------------------------------------
// K4: post-attention tail per 16-row tile. 1024 threads, split-K-4.
// Staging step now also performs the two-partial flash merge of k3's output.
// ---------------------------------------------------------------------------
__global__ __launch_bounds__(1024) void k4_tail(
    const u16* __restrict__ Wh, const u16* __restrict__ Wl,
    const float* __restrict__ OP, const float* __restrict__ ML,
    const float* __restrict__ SPATIAL32,
    const float* __restrict__ ao_b, const float* __restrict__ n1_g, const float* __restrict__ n1_b,
    const float* __restrict__ f1_b, const float* __restrict__ f2_b,
    const float* __restrict__ n2_g, const float* __restrict__ n2_b,
    const float* __restrict__ op_b, float* __restrict__ OUT)
{
  __shared__ __align__(16) u16 smem[25088];   // buf1 2x4224 (O/X1/X2) + buf2 2x8320 (F)
  __shared__ float redbuf[128];
  __shared__ float PART[3 * 16 * 260];        // split-K partials (row stride 260)
  u16* B1h = smem;             // 16 x 264
  u16* B1l = smem + 4224;
  u16* Fh  = smem + 8448;      // 16 x 520
  u16* Fl  = smem + 16768;

  const int t = threadIdx.x;
  const int w = t >> 6, lane = t & 63;
  const int ww = w & 3, set = w >> 2;
  const int lm = lane & 15, kg = lane >> 4;
  const int m0 = blockIdx.x * 16;

  // ---- stage O tile: merge the two k3 partials, write bf16x2 to LDS ----
  {
    if (t < 512) {
      const int row = t >> 5, cg = t & 31;
      const int c = cg * 8;
      const int hh_ = cg >> 3;                 // head = c/64
      const int grow = m0 + row;
      const float m0v = ML[grow * 8 + hh_ * 2],         l0v = ML[grow * 8 + hh_ * 2 + 1];
      const float m1v = ML[32768 + grow * 8 + hh_ * 2], l1v = ML[32768 + grow * 8 + hh_ * 2 + 1];
      const float mn = fmaxf(m0v, m1v);
      const float a0 = expf(m0v - mn), a1 = expf(m1v - mn);
      const float inv = 1.0f / (l0v * a0 + l1v * a1);
      const float4 v0a = *(const float4*)&OP[(size_t)grow * 256 + c];
      const float4 v0b = *(const float4*)&OP[(size_t)grow * 256 + c + 4];
      const float4 v1a = *(const float4*)&OP[1048576 + (size_t)grow * 256 + c];
      const float4 v1b = *(const float4*)&OP[1048576 + (size_t)grow * 256 + c + 4];
      const float mv[8] = {
        (v0a.x * a0 + v1a.x * a1) * inv, (v0a.y * a0 + v1a.y * a1) * inv,
        (v0a.z * a0 + v1a.z * a1) * inv, (v0a.w * a0 + v1a.w * a1) * inv,
        (v0b.x * a0 + v1b.x * a1) * inv, (v0b.y * a0 + v1b.y * a1) * inv,
        (v0b.z * a0 + v1b.z * a1) * inv, (v0b.w * a0 + v1b.w * a1) * inv };
      u64 ph0 = 0, pl0 = 0, ph1 = 0, pl1 = 0;
      #pragma unroll
      for (int i = 0; i < 4; i++) {
        u16 hx, lx; split_bf16(mv[i], hx, lx);
        ph0 |= ((u64)hx) << (16 * i); pl0 |= ((u64)lx) << (16 * i);
      }
      #pragma unroll
      for (int i = 0; i < 4; i++) {
        u16 hx, lx; split_bf16(mv[4 + i], hx, lx);
        ph1 |= ((u64)hx) << (16 * i); pl1 |= ((u64)lx) << (16 * i);
      }
      *(u64*)&B1h[row * 264 + c]     = ph0;
      *(u64*)&B1h[row * 264 + c + 4] = ph1;
      *(u64*)&B1l[row * 264 + c]     = pl0;
      *(u64*)&B1l[row * 264 + c + 4] = pl1;
    }
    __syncthreads();
  }

  // ---- step1: X1 = LN(spatial + O @ ao^T + b) ----
  floatx4 acc[4];
  #pragma unroll
  for (int j = 0; j < 4; j++) acc[j] = (floatx4){0.f,0.f,0.f,0.f};
  mm16_ks<4, 256, 4>(B1h, B1l, 264, Wh + W_AO, Wl + W_AO, acc);
  reduce_sets<4>(acc, PART);

  float x1reg[4][4];
  {
    float v[4][4];
    if (set == 0) {
      #pragma unroll
      for (int nj = 0; nj < 4; nj++) {
        const int col = ww * 64 + nj * 16 + lm;
        #pragma unroll
        for (int r = 0; r < 4; r++)
          v[nj][r] = acc[nj][r] + ao_b[col] + SPATIAL32[(size_t)(m0 + kg * 4 + r) * 256 + col];
      }
    } else {
      #pragma unroll
      for (int nj = 0; nj < 4; nj++)
        #pragma unroll
        for (int r = 0; r < 4; r++) v[nj][r] = 0.0f;
    }
    float mean[4], rstd[4];
    ln_rows16<256, 4>(v, redbuf, redbuf + 64, mean, rstd);
    if (set == 0) {
      #pragma unroll
      for (int nj = 0; nj < 4; nj++) {
        const int col = ww * 64 + nj * 16 + lm;
        #pragma unroll
        for (int r = 0; r < 4; r++) {
          const float y = n1_g[col] * (v[nj][r] - mean[r]) * rstd[r] + n1_b[col];
          x1reg[nj][r] = y;
          u16 h, l; split_bf16(y, h, l);
          B1h[(kg * 4 + r) * 264 + col] = h;   // X1 overwrites O
          B1l[(kg * 4 + r) * 264 + col] = l;
        }
      }
    }
  }
  __syncthreads();

  // ---- step2: F1 = gelu(X1 @ f1^T + b), two 256-col passes ----
  #pragma unroll
  for (int ct = 0; ct < 2; ct++) {
    floatx4 a4[4];
    #pragma unroll
    for (int j = 0; j < 4; j++) a4[j] = (floatx4){0.f,0.f,0.f,0.f};
    mm16_ks<4, 256, 4>(B1h, B1l, 264,
                       Wh + W_F1 + (size_t)ct * 65536, Wl + W_F1 + (size_t)ct * 65536, a4);
    reduce_sets<4>(a4, PART);
    if (set == 0) {
      #pragma unroll
      for (int nj = 0; nj < 4; nj++) {
        const int col = ct * 256 + ww * 64 + nj * 16 + lm;
        #pragma unroll
        for (int r = 0; r < 4; r++) {
          const float y = gelu_f(a4[nj][r] + f1_b[col]);
          u16 h, l; split_bf16(y, h, l);
          Fh[(kg * 4 + r) * 520 + col] = h;
          Fl[(kg * 4 + r) * 520 + col] = l;
        }
      }
    }
  }
  __syncthreads();

  // ---- step3: X2 = LN(X1 + F1 @ f2^T + b) ----
  #pragma unroll
  for (int j = 0; j < 4; j++) acc[j] = (floatx4){0.f,0.f,0.f,0.f};
  mm16_ks<4, 512, 4>(Fh, Fl, 520, Wh + W_F2, Wl + W_F2, acc);
  reduce_sets<4>(acc, PART);
  {
    float v[4][4];
    if (set == 0) {
      #pragma unroll
      for (int nj = 0; nj < 4; nj++) {
        const int col = ww * 64 + nj * 16 + lm;
        #pragma unroll
        for (int r = 0; r < 4; r++)
          v[nj][r] = acc[nj][r] + f2_b[col] + x1reg[nj][r];
      }
    } else {
      #pragma unroll
      for (int nj = 0; nj < 4; nj++)
        #pragma unroll
        for (int r = 0; r < 4; r++) v[nj][r] = 0.0f;
    }
    float mean[4], rstd[4];
    ln_rows16<256, 4>(v, redbuf, redbuf + 64, mean, rstd);
    if (set == 0) {
      #pragma unroll
      for (int nj = 0; nj < 4; nj++) {
        const int col = ww * 64 + nj * 16 + lm;
        #pragma unroll
        for (int r = 0; r < 4; r++) {
          const float y = n2_g[col] * (v[nj][r] - mean[r]) * rstd[r] + n2_b[col];
          u16 h, l; split_bf16(y, h, l);
          B1h[(kg * 4 + r) * 264 + col] = h;   // X2 overwrites X1
          B1l[(kg * 4 + r) * 264 + col] = l;
        }
      }
    }
  }
  __syncthreads();

  // ---- step4: OUT = X2 @ op^T + b ----
  #pragma unroll
  for (int j = 0; j < 4; j++) acc[j] = (floatx4){0.f,0.f,0.f,0.f};
  mm16_ks<4, 256, 4>(B1h, B1l, 264, Wh + W_OP, Wl + W_OP, acc);
  reduce_sets<4>(acc, PART);
  if (set == 0) {
    #pragma unroll
    for (int nj = 0; nj < 4; nj++) {
      const int col = ww * 64 + nj * 16 + lm;
      #pragma unroll
      for (int r = 0; r < 4; r++)
        OUT[(size_t)(m0 + kg * 4 + r) * 256 + col] = acc[nj][r] + op_b[col];
    }
  }
}

// ---------------------------------------------------------------------------
extern "C" void kernel_launch(void* const* d_in, const int* in_sizes, int n_in,
                              void* d_out, int out_size, void* d_ws, size_t ws_size,
                              hipStream_t stream) {
  const float* image   = (const float*)d_in[0];
  const float* coords  = (const float*)d_in[1];
  const int*   labels  = (const int*)d_in[2];
  const float* pe_w    = (const float*)d_in[3];
  const float* pe_b    = (const float*)d_in[4];
  const float* temb    = (const float*)d_in[5];
  const float* fbi     = (const float*)d_in[6];
  const float* fe1_w   = (const float*)d_in[7];
  const float* fe1_b   = (const float*)d_in[8];
  const float* feln1_g = (const float*)d_in[9];
  const float* feln1_b = (const float*)d_in[10];
  const float* fe2_w   = (const float*)d_in[11];
  const float* fe2_b   = (const float*)d_in[12];
  const float* feln2_g = (const float*)d_in[13];
  const float* feln2_b = (const float*)d_in[14];
  const float* in_w    = (const float*)d_in[15];
  const float* in_b    = (const float*)d_in[16];
  const float* ao_w    = (const float*)d_in[17];
  const float* ao_b    = (const float*)d_in[18];
  const float* n1_g    = (const float*)d_in[19];
  const float* n1_b    = (const float*)d_in[20];
  const float* f1_w    = (const float*)d_in[21];
  const float* f1_b    = (const float*)d_in[22];
  const float* f2_w    = (const float*)d_in[23];
  const float* f2_b    = (const float*)d_in[24];
  const float* n2_g    = (const float*)d_in[25];
  const float* n2_b    = (const float*)d_in[26];
  const float* op_w    = (const float*)d_in[27];
  const float* op_b    = (const float*)d_in[28];

  float* ws = (float*)d_ws;
  float* SPATIAL32 = ws;                       // 1M floats
  u16* S = (u16*)(ws + 2 * (1u << 20));
  u16* Wh = S;
  u16* Wl = S + 690176;
  u16* PEh   = S + 1380352;  u16* PEl   = PEh + 1048576;
  u16* FEATh = S + 3477504;  u16* FEATl = FEATh + 65536;
  u16* FQh   = S + 4657152;  u16* FQl   = FQh + 1048576;
  u16* SPh   = S + 6754304;  u16* SPl   = SPh + 1048576;
  u16* Qh    = S + 8851456;  u16* Ql    = Qh + 1048576;
  u16* Kh    = S + 10948608; u16* Kl    = Kh + 1048576;
  u16* Vth   = S + 13045760; u16* Vtl   = Vth + 1048576;
  float* OP  = (float*)(S + 15142912);   // 2 x 4096x256 f32 partial O
  float* ML  = (float*)(S + 19337216);   // 2 x 4096x4 (m,l) pairs

  float* OUT = (float*)d_out;

  k0_prep<<<6792, 64, 0, stream>>>(
      image, coords, fbi, pe_w, fe1_w, fe2_w, in_w, ao_w, f1_w, f2_w, op_w,
      Wh, Wl, PEh, PEl, FEATh, FEATl);
  k1_front<<<512, 256, 0, stream>>>(
      Wh, Wl, PEh, PEl, FEATh, FEATl, pe_b, labels, temb,
      fe1_b, feln1_g, feln1_b, fe2_b, feln2_g, feln2_b,
      SPATIAL32, SPh, SPl, FQh, FQl);
  k2_qkv<<<768, 512, 0, stream>>>(
      Wh, Wl, SPh, SPl, FQh, FQl, in_b, Qh, Ql, Kh, Kl, Vth, Vtl);
  k3_attn<<<512, 256, 0, stream>>>(Qh, Ql, Kh, Kl, Vth, Vtl, OP, ML);
  k4_tail<<<256, 1024, 0, stream>>>(
      Wh, Wl, OP, ML, SPATIAL32, ao_b, n1_g, n1_b, f1_b, f2_b, n2_g, n2_b, op_b, OUT);
}

// Round 7
// 286.959 us; speedup vs baseline: 1.0673x; 1.0673x over previous
//
#include <hip/hip_runtime.h>
#include <math.h>

// B=8, C=3, H=1024, W=1024, N=512, D=256, PS=16, NB=8, NH=4, hd=64
// tokens M = B*N = 4096

typedef __attribute__((ext_vector_type(8))) short short8;
typedef __attribute__((ext_vector_type(4))) float floatx4;
typedef unsigned short u16;
typedef unsigned long long u64;

__device__ __forceinline__ float gelu_f(float x) {
  return 0.5f * x * (1.0f + erff(x * 0.70710678118654752f));
}

__device__ __forceinline__ u16 bf16_rn(float x) {
  union { float f; unsigned u; } v; v.f = x;
  unsigned r = v.u + 0x7fffu + ((v.u >> 16) & 1u);
  return (u16)(r >> 16);
}

__device__ __forceinline__ void split_bf16(float x, u16& h, u16& l) {
  h = bf16_rn(x);
  union { unsigned u; float f; } hv; hv.u = ((unsigned)h) << 16;
  l = bf16_rn(x - hv.f);
}

// weight segment offsets (elements)
#define W_PE   0
#define W_FE1  65536
#define W_FE2  67584
#define W_IN   100352
#define W_AO   296960
#define W_F1   362496
#define W_F2   493568
#define W_OP   624640

// ---------------------------------------------------------------------------
// Weights (except fe1) are stored FRAGMENT-MAJOR:
//   element (n,k) of an N x K matrix lives at
//   ((n>>4)*(K>>5) + (k>>5))*512 + (((k>>3)&3)*16 + (n&15))*8 + (k&7)
// ---------------------------------------------------------------------------

// mm16_swz: 16 rows x (4*NA*16) cols GEMM, bf16x3.  (4-wave blocks: k1)
template <int NA, int K>
__device__ __forceinline__ void mm16_swz(
    const u16* Ah, const u16* Al, const int S,
    const u16* __restrict__ Bh, const u16* __restrict__ Bl,
    floatx4* acc)
{
  const int t = threadIdx.x;
  const int w = t >> 6, lane = t & 63;
  const int lm = lane & 15, kg = lane >> 4;
  #pragma unroll
  for (int it = 0; it < K / 32; ++it) {
    const short8 a_h = *(const short8*)&Ah[lm * S + it * 32 + kg * 8];
    const short8 a_l = *(const short8*)&Al[lm * S + it * 32 + kg * 8];
    #pragma unroll
    for (int nj = 0; nj < NA; nj++) {
      const size_t wo = (size_t)(((w * NA + nj) * (K / 32) + it) * 512 + lane * 8);
      const short8 b_h = *(const short8*)&Bh[wo];
      const short8 b_l = *(const short8*)&Bl[wo];
      acc[nj] = __builtin_amdgcn_mfma_f32_16x16x32_bf16(a_h, b_h, acc[nj], 0, 0, 0);
      acc[nj] = __builtin_amdgcn_mfma_f32_16x16x32_bf16(a_h, b_l, acc[nj], 0, 0, 0);
      acc[nj] = __builtin_amdgcn_mfma_f32_16x16x32_bf16(a_l, b_h, acc[nj], 0, 0, 0);
    }
  }
}

// mm16_ks: same GEMM, K split NSETS ways across wave-sets (k2: 2, k4: 4).
template <int NA, int K, int NSETS>
__device__ __forceinline__ void mm16_ks(
    const u16* Ah, const u16* Al, const int S,
    const u16* __restrict__ Bh, const u16* __restrict__ Bl,
    floatx4* acc)
{
  const int t = threadIdx.x;
  const int w = t >> 6, lane = t & 63;
  const int ww = w & 3, set = w >> 2;
  const int lm = lane & 15, kg = lane >> 4;
  constexpr int ITERS = K / (32 * NSETS);
  #pragma unroll
  for (int itl = 0; itl < ITERS; ++itl) {
    const int it = set * ITERS + itl;
    const short8 a_h = *(const short8*)&Ah[lm * S + it * 32 + kg * 8];
    const short8 a_l = *(const short8*)&Al[lm * S + it * 32 + kg * 8];
    #pragma unroll
    for (int nj = 0; nj < NA; nj++) {
      const size_t wo = (size_t)(((ww * NA + nj) * (K / 32) + it) * 512 + lane * 8);
      const short8 b_h = *(const short8*)&Bh[wo];
      const short8 b_l = *(const short8*)&Bl[wo];
      acc[nj] = __builtin_amdgcn_mfma_f32_16x16x32_bf16(a_h, b_h, acc[nj], 0, 0, 0);
      acc[nj] = __builtin_amdgcn_mfma_f32_16x16x32_bf16(a_h, b_l, acc[nj], 0, 0, 0);
      acc[nj] = __builtin_amdgcn_mfma_f32_16x16x32_bf16(a_l, b_h, acc[nj], 0, 0, 0);
    }
  }
}

// reduce the 4 wave-set partials into set 0's acc (k4). PART rows stride 260.
template <int NA>
__device__ __forceinline__ void reduce_sets(floatx4* acc, float* PART)
{
  const int t = threadIdx.x;
  const int w = t >> 6, lane = t & 63;
  const int ww = w & 3, set = w >> 2;
  const int lm = lane & 15, kg = lane >> 4;
  __syncthreads();
  if (set != 0) {
    #pragma unroll
    for (int nj = 0; nj < NA; nj++) {
      const int col = ww * (NA * 16) + nj * 16 + lm;
      #pragma unroll
      for (int r = 0; r < 4; r++)
        PART[((set - 1) * 16 + kg * 4 + r) * 260 + col] = acc[nj][r];
    }
  }
  __syncthreads();
  if (set == 0) {
    #pragma unroll
    for (int nj = 0; nj < NA; nj++) {
      const int col = ww * (NA * 16) + nj * 16 + lm;
      #pragma unroll
      for (int r = 0; r < 4; r++) {
        const int rr = kg * 4 + r;
        acc[nj][r] += PART[rr * 260 + col] + PART[(16 + rr) * 260 + col]
                    + PART[(32 + rr) * 260 + col];
      }
    }
  }
}

// reduce 2 wave-set partials into set 0's acc (k2).
template <int NA>
__device__ __forceinline__ void reduce_sets2(floatx4* acc, float* PART)
{
  const int t = threadIdx.x;
  const int w = t >> 6, lane = t & 63;
  const int ww = w & 3, set = w >> 2;
  const int lm = lane & 15, kg = lane >> 4;
  __syncthreads();
  if (set == 1) {
    #pragma unroll
    for (int nj = 0; nj < NA; nj++) {
      const int col = ww * (NA * 16) + nj * 16 + lm;
      #pragma unroll
      for (int r = 0; r < 4; r++)
        PART[(kg * 4 + r) * 260 + col] = acc[nj][r];
    }
  }
  __syncthreads();
  if (set == 0) {
    #pragma unroll
    for (int nj = 0; nj < NA; nj++) {
      const int col = ww * (NA * 16) + nj * 16 + lm;
      #pragma unroll
      for (int r = 0; r < 4; r++)
        acc[nj][r] += PART[(kg * 4 + r) * 260 + col];
    }
  }
}

// coalesced global->LDS staging of a 16x256 u16 tile pair (stride 264), 256 thr
__device__ __forceinline__ void stage16(
    const u16* __restrict__ Gh, const u16* __restrict__ Gl,
    u16* Lh, u16* Ll)
{
  const int t = threadIdx.x;
  #pragma unroll
  for (int i = 0; i < 2; i++) {
    const int s = t + i * 256;
    const int row = s >> 5, c = (s & 31) * 8;
    *(short8*)&Lh[row * 264 + c] = *(const short8*)&Gh[(size_t)row * 256 + c];
    *(short8*)&Ll[row * 264 + c] = *(const short8*)&Gl[(size_t)row * 256 + c];
  }
  __syncthreads();
}

// per-row LayerNorm stats (4-wave blocks: k1)
template <int N_, int NA>
__device__ __forceinline__ void ln_rows(const float (&v)[NA][4], float* red1, float* red2,
                                        float (&mean)[4], float (&rstd)[4])
{
  const int t = threadIdx.x;
  const int w = t >> 6;
  const int lane = t & 63;
  const int kg = lane >> 4;
  float s1[4] = {0.f,0.f,0.f,0.f}, s2[4] = {0.f,0.f,0.f,0.f};
  #pragma unroll
  for (int nj = 0; nj < NA; nj++)
    #pragma unroll
    for (int r = 0; r < 4; r++) { s1[r] += v[nj][r]; s2[r] += v[nj][r] * v[nj][r]; }
  #pragma unroll
  for (int r = 0; r < 4; r++) {
    #pragma unroll
    for (int off = 1; off < 16; off <<= 1) {
      s1[r] += __shfl_xor(s1[r], off);
      s2[r] += __shfl_xor(s2[r], off);
    }
  }
  __syncthreads();
  if ((lane & 15) == 0) {
    #pragma unroll
    for (int r = 0; r < 4; r++) {
      red1[w * 16 + kg * 4 + r] = s1[r];
      red2[w * 16 + kg * 4 + r] = s2[r];
    }
  }
  __syncthreads();
  #pragma unroll
  for (int r = 0; r < 4; r++) {
    const int rw = kg * 4 + r;
    const float a = red1[rw] + red1[16 + rw] + red1[32 + rw] + red1[48 + rw];
    const float b = red2[rw] + red2[16 + rw] + red2[32 + rw] + red2[48 + rw];
    mean[r] = a * (1.0f / N_);
    rstd[r] = rsqrtf(b * (1.0f / N_) - mean[r] * mean[r] + 1e-5f);
  }
}

// LN for 16-wave split-K blocks (k4); only set 0's stats count.
template <int N_, int NA>
__device__ __forceinline__ void ln_rows16(const float (&v)[NA][4], float* red1, float* red2,
                                          float (&mean)[4], float (&rstd)[4])
{
  const int t = threadIdx.x;
  const int w = t >> 6;
  const int lane = t & 63;
  const int ww = w & 3, set = w >> 2;
  const int kg = lane >> 4;
  float s1[4] = {0.f,0.f,0.f,0.f}, s2[4] = {0.f,0.f,0.f,0.f};
  #pragma unroll
  for (int nj = 0; nj < NA; nj++)
    #pragma unroll
    for (int r = 0; r < 4; r++) { s1[r] += v[nj][r]; s2[r] += v[nj][r] * v[nj][r]; }
  #pragma unroll
  for (int r = 0; r < 4; r++) {
    #pragma unroll
    for (int off = 1; off < 16; off <<= 1) {
      s1[r] += __shfl_xor(s1[r], off);
      s2[r] += __shfl_xor(s2[r], off);
    }
  }
  __syncthreads();
  if (set == 0 && (lane & 15) == 0) {
    #pragma unroll
    for (int r = 0; r < 4; r++) {
      red1[ww * 16 + kg * 4 + r] = s1[r];
      red2[ww * 16 + kg * 4 + r] = s2[r];
    }
  }
  __syncthreads();
  if (set == 0) {
    #pragma unroll
    for (int r = 0; r < 4; r++) {
      const int rw = kg * 4 + r;
      const float a = red1[rw] + red1[16 + rw] + red1[32 + rw] + red1[48 + rw];
      const float b = red2[rw] + red2[16 + rw] + red2[32 + rw] + red2[48 + rw];
      mean[r] = a * (1.0f / N_);
      rstd[r] = rsqrtf(b * (1.0f / N_) - mean[r] * mean[r] + 1e-5f);
    }
  }
}

// store 4 consecutive (same-n) elements into fragment-major layout
__device__ __forceinline__ void store_swz(
    u16* __restrict__ Wh, u16* __restrict__ Wl, const int segbase,
    const int rel, const int kshift, const float4 v)
{
  const int K = 1 << kshift;
  const int n = rel >> kshift;
  const int k = rel & (K - 1);
  const int off8 = ((n >> 4) * (K >> 5) + (k >> 5)) * 512
                 + (((k >> 3) & 3) * 16 + (n & 15)) * 8 + (k & 7);
  u16 h0,h1,h2,h3,l0,l1,l2,l3;
  split_bf16(v.x,h0,l0); split_bf16(v.y,h1,l1);
  split_bf16(v.z,h2,l2); split_bf16(v.w,h3,l3);
  *(u64*)&Wh[segbase + off8] = (u64)h0 | ((u64)h1<<16) | ((u64)h2<<32) | ((u64)h3<<48);
  *(u64*)&Wl[segbase + off8] = (u64)l0 | ((u64)l1<<16) | ((u64)l2<<32) | ((u64)l3<<48);
}

// ---------------------------------------------------------------------------
// K0: weight split+swizzle (blocks 0..2695) + featurize (2696..6791), 64 thr
// ---------------------------------------------------------------------------
__global__ __launch_bounds__(64) void k0_prep(
    const float* __restrict__ image, const float* __restrict__ coords,
    const float* __restrict__ fbi,
    const float* __restrict__ pe_w, const float* __restrict__ fe1_w,
    const float* __restrict__ fe2_w, const float* __restrict__ in_w,
    const float* __restrict__ ao_w, const float* __restrict__ f1_w,
    const float* __restrict__ f2_w, const float* __restrict__ op_w,
    u16* __restrict__ Wh, u16* __restrict__ Wl,
    u16* __restrict__ PEh, u16* __restrict__ PEl,
    u16* __restrict__ FEATh, u16* __restrict__ FEATl)
{
  const int blk = blockIdx.x;
  const int lane = threadIdx.x;

  if (blk < 2696) {
    const int idx = (blk * 64 + lane) * 4;
    if (idx < W_FE1) {
      store_swz(Wh, Wl, W_PE, idx - W_PE, 8, *(const float4*)&pe_w[idx - W_PE]);
    } else if (idx < W_FE2) {
      const int rel = idx - W_FE1;
      const float4 v = *(const float4*)&fe1_w[rel];
      u16 h0,h1,h2,h3,l0,l1,l2,l3;
      split_bf16(v.x,h0,l0); split_bf16(v.y,h1,l1);
      split_bf16(v.z,h2,l2); split_bf16(v.w,h3,l3);
      *(u64*)&Wh[idx] = (u64)h0 | ((u64)h1<<16) | ((u64)h2<<32) | ((u64)h3<<48);
      *(u64*)&Wl[idx] = (u64)l0 | ((u64)l1<<16) | ((u64)l2<<32) | ((u64)l3<<48);
    } else if (idx < W_IN) {
      store_swz(Wh, Wl, W_FE2, idx - W_FE2, 7, *(const float4*)&fe2_w[idx - W_FE2]);
    } else if (idx < W_AO) {
      store_swz(Wh, Wl, W_IN, idx - W_IN, 8, *(const float4*)&in_w[idx - W_IN]);
    } else if (idx < W_F1) {
      store_swz(Wh, Wl, W_AO, idx - W_AO, 8, *(const float4*)&ao_w[idx - W_AO]);
    } else if (idx < W_F2) {
      store_swz(Wh, Wl, W_F1, idx - W_F1, 8, *(const float4*)&f1_w[idx - W_F1]);
    } else if (idx < W_OP) {
      store_swz(Wh, Wl, W_F2, idx - W_F2, 9, *(const float4*)&f2_w[idx - W_F2]);
    } else {
      store_swz(Wh, Wl, W_OP, idx - W_OP, 8, *(const float4*)&op_w[idx - W_OP]);
    }
    return;
  }

  const int id = blk - 2696;
  const int b  = id >> 9;
  const float pcx = coords[id * 2 + 0];
  const float pcy = coords[id * 2 + 1];

  {
    const float TWO_PI = 6.283185307179586f;
    const float dimt = expf((float)lane * 0.28782313662425572f); // ln(1e4)/32
    const float ax = (pcx * (1.0f / 1024.0f)) * TWO_PI / dimt;
    const float ay = (pcy * (1.0f / 1024.0f)) * TWO_PI / dimt;
    u16 h, l;
    split_bf16(sinf(ax), h, l); PEh[id*256+lane]     = h; PEl[id*256+lane]     = l;
    split_bf16(cosf(ax), h, l); PEh[id*256+lane+64]  = h; PEl[id*256+lane+64]  = l;
    split_bf16(sinf(ay), h, l); PEh[id*256+lane+128] = h; PEl[id*256+lane+128] = l;
    split_bf16(cosf(ay), h, l); PEh[id*256+lane+192] = h; PEl[id*256+lane+192] = l;
  }

  int px = (int)pcx; px = px < 8 ? 8 : (px > 1015 ? 1015 : px);
  int py = (int)pcy; py = py < 8 ? 8 : (py > 1015 ? 1015 : py);

  __shared__ float patch[256];
  __shared__ float ct[16], st[16];
  __shared__ float Gre[144], Gim[144];
  __shared__ float msum[8], psum[8];
  __shared__ int cnt8[8];
  {
    const float* img = image + (size_t)b * 3145728;
    #pragma unroll
    for (int i = 0; i < 4; i++) {
      const int p = i * 64 + lane;
      const int r = p >> 4, c = p & 15;
      const int off = (py - 8 + r) * 1024 + (px - 8 + c);
      const float s = img[off] + img[off + 1048576] + img[off + 2097152];
      patch[r * 16 + c] = s * (1.0f / 3.0f);
    }
  }
  if (lane < 16) {
    float c, s;
    if ((lane & 3) == 0) {
      const float cv[4] = {1.0f, 0.0f, -1.0f, 0.0f};
      const float sv[4] = {0.0f, -1.0f, 0.0f, 1.0f};
      c = cv[lane >> 2]; s = sv[lane >> 2];
    } else {
      const float a = -3.14159265358979f * (float)lane * 0.125f;
      c = cosf(a); s = sinf(a);
    }
    ct[lane] = c; st[lane] = s;
  }
  if (lane < 8) { msum[lane] = 0.0f; psum[lane] = 0.0f; cnt8[lane] = 0; }
  __syncthreads();

  for (int tt = lane; tt < 144; tt += 64) {
    const int y = tt / 9, kx = tt - y * 9;
    float re = 0.0f, im = 0.0f;
    #pragma unroll
    for (int x = 0; x < 16; x++) {
      const int w = (x * kx) & 15;
      const float pv = patch[y * 16 + x];
      re = fmaf(pv, ct[w], re);
      im = fmaf(pv, st[w], im);
    }
    Gre[tt] = re; Gim[tt] = im;
  }
  __syncthreads();

  for (int tt = lane; tt < 144; tt += 64) {
    const int ky = tt / 9, kx = tt - ky * 9;
    float re = 0.0f, im = 0.0f;
    #pragma unroll
    for (int y = 0; y < 16; y++) {
      const int w = (y * ky) & 15;
      const float gr = Gre[y * 9 + kx], gi = Gim[y * 9 + kx];
      re = fmaf(gr, ct[w], re);
      re = fmaf(-gi, st[w], re);
      im = fmaf(gr, st[w], im);
      im = fmaf(gi, ct[w], im);
    }
    if (((ky & 7) == 0) && ((kx & 7) == 0)) im = 0.0f;
    const float mag = sqrtf(re * re + im * im) * 0.0625f;
    const float ph  = atan2f(im, re);

    const float fy = (ky < 8) ? (float)ky * 0.0625f : (float)(ky - 16) * 0.0625f;
    const float fx = (float)kx * 0.0625f;
    const float r = sqrtf(fx * fx + fy * fy);
    const float max_r = 0.7071077811865476f;
    const float stepf = max_r * 0.125f;
    int idx = 0;
    #pragma unroll
    for (int kq = 1; kq <= 8; kq++) {
      const float e = (kq == 8) ? max_r : stepf * (float)kq;
      if (r >= e) idx = kq;
    }
    if (idx > 7) idx = 7;
    atomicAdd(&msum[idx], mag);
    atomicAdd(&psum[idx], ph);
    atomicAdd(&cnt8[idx], 1);
  }
  __syncthreads();

  if (lane < 8) {
    float fm = fbi[0];
    #pragma unroll
    for (int j = 1; j < 8; j++) fm = fmaxf(fm, fbi[j]);
    float se = 0.0f;
    #pragma unroll
    for (int j = 0; j < 8; j++) se += expf(fbi[j] - fm);
    const float smx = expf(fbi[lane] - fm) / se;
    const float c = (float)(cnt8[lane] > 0 ? cnt8[lane] : 1);
    u16 h, l;
    split_bf16((msum[lane] / c) * smx, h, l);
    FEATh[id*16+lane] = h; FEATl[id*16+lane] = l;
    split_bf16(psum[lane] / c, h, l);
    FEATh[id*16+8+lane] = h; FEATl[id*16+8+lane] = l;
  }
}

// ---------------------------------------------------------------------------
// K1: blocks 0..255 spatial (staged A, swz B); 256..511 freq-MLP  (unchanged)
// ---------------------------------------------------------------------------
__global__ __launch_bounds__(256) void k1_front(
    const u16* __restrict__ Wh, const u16* __restrict__ Wl,
    const u16* __restrict__ PEh, const u16* __restrict__ PEl,
    const u16* __restrict__ FEATh, const u16* __restrict__ FEATl,
    const float* __restrict__ pe_b, const int* __restrict__ labels,
    const float* __restrict__ temb,
    const float* __restrict__ fe1_b, const float* __restrict__ feln1_g, const float* __restrict__ feln1_b,
    const float* __restrict__ fe2_b, const float* __restrict__ feln2_g, const float* __restrict__ feln2_b,
    float* __restrict__ SPATIAL32, u16* __restrict__ SPh, u16* __restrict__ SPl,
    u16* __restrict__ FQh, u16* __restrict__ FQl)
{
  __shared__ __align__(16) u16 smem[8448];
  __shared__ float redbuf[128];
  const int blk = blockIdx.x;
  const int t = threadIdx.x;
  const int w = t >> 6, lane = t & 63;
  const int lm = lane & 15, kg = lane >> 4;

  if (blk < 256) {
    const int m0 = blk * 16;
    u16* Lh = smem;          // 16 x 264
    u16* Ll = smem + 4224;
    stage16(PEh + (size_t)m0 * 256, PEl + (size_t)m0 * 256, Lh, Ll);
    floatx4 acc[4];
    #pragma unroll
    for (int j = 0; j < 4; j++) acc[j] = (floatx4){0.f,0.f,0.f,0.f};
    mm16_swz<4, 256>(Lh, Ll, 264, Wh + W_PE, Wl + W_PE, acc);
    #pragma unroll
    for (int nj = 0; nj < 4; nj++) {
      const int col = w * 64 + nj * 16 + lm;
      #pragma unroll
      for (int r = 0; r < 4; r++) {
        const int row = m0 + kg * 4 + r;
        const float v = acc[nj][r] + pe_b[col] + temb[labels[row] * 256 + col];
        SPATIAL32[(size_t)row * 256 + col] = v;
        u16 h, l; split_bf16(v, h, l);
        SPh[(size_t)row * 256 + col] = h;
        SPl[(size_t)row * 256 + col] = l;
      }
    }
    return;
  }

  const int m0 = (blk - 256) * 16;
  u16* h1h = smem;           // 16 x 136
  u16* h1l = smem + 2176;

  floatx4 acc1[2];
  acc1[0] = (floatx4){0.f,0.f,0.f,0.f};
  acc1[1] = (floatx4){0.f,0.f,0.f,0.f};
  {
    const short8 zz = {0,0,0,0,0,0,0,0};
    const short8 a_h = (kg < 2) ? *(const short8*)&FEATh[(size_t)(m0 + lm) * 16 + kg * 8] : zz;
    const short8 a_l = (kg < 2) ? *(const short8*)&FEATl[(size_t)(m0 + lm) * 16 + kg * 8] : zz;
    #pragma unroll
    for (int nj = 0; nj < 2; nj++) {
      const int col = w * 32 + nj * 16 + lm;
      const short8 b_h = (kg < 2) ? *(const short8*)&Wh[W_FE1 + (size_t)col * 16 + kg * 8] : zz;
      const short8 b_l = (kg < 2) ? *(const short8*)&Wl[W_FE1 + (size_t)col * 16 + kg * 8] : zz;
      acc1[nj] = __builtin_amdgcn_mfma_f32_16x16x32_bf16(a_h, b_h, acc1[nj], 0, 0, 0);
      acc1[nj] = __builtin_amdgcn_mfma_f32_16x16x32_bf16(a_h, b_l, acc1[nj], 0, 0, 0);
      acc1[nj] = __builtin_amdgcn_mfma_f32_16x16x32_bf16(a_l, b_h, acc1[nj], 0, 0, 0);
    }
  }

  float v1[2][4];
  #pragma unroll
  for (int nj = 0; nj < 2; nj++) {
    const int col = w * 32 + nj * 16 + lm;
    #pragma unroll
    for (int r = 0; r < 4; r++) v1[nj][r] = acc1[nj][r] + fe1_b[col];
  }
  float mean[4], rstd[4];
  ln_rows<128, 2>(v1, redbuf, redbuf + 64, mean, rstd);
  #pragma unroll
  for (int nj = 0; nj < 2; nj++) {
    const int col = w * 32 + nj * 16 + lm;
    #pragma unroll
    for (int r = 0; r < 4; r++) {
      float y = feln1_g[col] * (v1[nj][r] - mean[r]) * rstd[r] + feln1_b[col];
      y = gelu_f(y);
      u16 h, l; split_bf16(y, h, l);
      h1h[(kg * 4 + r) * 136 + col] = h;
      h1l[(kg * 4 + r) * 136 + col] = l;
    }
  }
  __syncthreads();

  floatx4 acc2[4];
  #pragma unroll
  for (int j = 0; j < 4; j++) acc2[j] = (floatx4){0.f,0.f,0.f,0.f};
  mm16_swz<4, 128>(h1h, h1l, 136, Wh + W_FE2, Wl + W_FE2, acc2);

  float v2[4][4];
  #pragma unroll
  for (int nj = 0; nj < 4; nj++) {
    const int col = w * 64 + nj * 16 + lm;
    #pragma unroll
    for (int r = 0; r < 4; r++) v2[nj][r] = acc2[nj][r] + fe2_b[col];
  }
  ln_rows<256, 4>(v2, redbuf, redbuf + 64, mean, rstd);
  #pragma unroll
  for (int nj = 0; nj < 4; nj++) {
    const int col = w * 64 + nj * 16 + lm;
    #pragma unroll
    for (int r = 0; r < 4; r++) {
      const int rw = m0 + kg * 4 + r;
      float y = feln2_g[col] * (v2[nj][r] - mean[r]) * rstd[r] + feln2_b[col];
      u16 h, l; split_bf16(y, h, l);
      FQh[(size_t)rw * 256 + col] = h;
      FQl[(size_t)rw * 256 + col] = l;
    }
  }
}

// ---------------------------------------------------------------------------
// K2: QKV projection, 512 threads, split-K-2  (unchanged from round 4)
// ---------------------------------------------------------------------------
__global__ __launch_bounds__(512) void k2_qkv(
    const u16* __restrict__ Wh, const u16* __restrict__ Wl,
    const u16* __restrict__ SPh, const u16* __restrict__ SPl,
    const u16* __restrict__ FQh, const u16* __restrict__ FQl,
    const float* __restrict__ in_b,
    u16* __restrict__ Qh, u16* __restrict__ Ql,
    u16* __restrict__ Kh, u16* __restrict__ Kl,
    u16* __restrict__ Vth, u16* __restrict__ Vtl)
{
  __shared__ __align__(16) u16 smem[8448];
  __shared__ float PART[16 * 260];
  const int bx = blockIdx.x;
  const int seg = bx >> 8;
  const int m0 = (bx & 255) * 16;
  const int t = threadIdx.x;
  const int w = t >> 6, lane = t & 63;
  const int ww = w & 3, set = w >> 2;
  const int lm = lane & 15, kg = lane >> 4;

  const u16 *Ah, *Al; const u16 *Wsh, *Wsl; const float* bias;
  if (seg == 0)      { Ah = SPh; Al = SPl; Wsh = Wh + W_IN;          Wsl = Wl + W_IN;          bias = in_b; }
  else if (seg == 1) { Ah = FQh; Al = FQl; Wsh = Wh + W_IN + 65536;  Wsl = Wl + W_IN + 65536;  bias = in_b + 256; }
  else               { Ah = FQh; Al = FQl; Wsh = Wh + W_IN + 131072; Wsl = Wl + W_IN + 131072; bias = in_b + 512; }

  u16* Lh = smem;
  u16* Ll = smem + 4224;
  {
    const u16* Gh = Ah + (size_t)m0 * 256;
    const u16* Gl = Al + (size_t)m0 * 256;
    const int row = t >> 5, c = (t & 31) * 8;
    *(short8*)&Lh[row * 264 + c] = *(const short8*)&Gh[(size_t)row * 256 + c];
    *(short8*)&Ll[row * 264 + c] = *(const short8*)&Gl[(size_t)row * 256 + c];
    __syncthreads();
  }

  floatx4 acc[4];
  #pragma unroll
  for (int j = 0; j < 4; j++) acc[j] = (floatx4){0.f,0.f,0.f,0.f};
  mm16_ks<4, 256, 2>(Lh, Ll, 264, Wsh, Wsl, acc);
  reduce_sets2<4>(acc, PART);

  if (set != 0) return;

  if (seg < 2) {
    u16* oh = (seg == 0) ? Qh : Kh;
    u16* ol = (seg == 0) ? Ql : Kl;
    #pragma unroll
    for (int nj = 0; nj < 4; nj++) {
      const int col = ww * 64 + nj * 16 + lm;
      #pragma unroll
      for (int r = 0; r < 4; r++) {
        const int row = m0 + kg * 4 + r;
        u16 h, l; split_bf16(acc[nj][r] + bias[col], h, l);
        oh[(size_t)row * 256 + col] = h;
        ol[(size_t)row * 256 + col] = l;
      }
    }
  } else {
    #pragma unroll
    for (int nj = 0; nj < 4; nj++) {
      const int col = ww * 64 + nj * 16 + lm;
      u64 hp = 0, lp = 0;
      #pragma unroll
      for (int r = 0; r < 4; r++) {
        u16 h, l; split_bf16(acc[nj][r] + bias[col], h, l);
        hp |= ((u64)h) << (16 * r);
        lp |= ((u64)l) << (16 * r);
      }
      *(u64*)&Vth[(size_t)col * 4096 + m0 + kg * 4] = hp;
      *(u64*)&Vtl[(size_t)col * 4096 + m0 + kg * 4] = lp;
    }
  }
}

// ---------------------------------------------------------------------------
// K3: flash attention, 512 blocks x 256 thr (unchanged from round 4):
// block (bh,qt,half) handles kt = half*4..half*4+3, writes UNNORMALIZED f32
// partial O + (m,l).
// ---------------------------------------------------------------------------
__global__ __launch_bounds__(256) void k3_attn(
    const u16* __restrict__ Qh, const u16* __restrict__ Ql,
    const u16* __restrict__ Kh, const u16* __restrict__ Kl,
    const u16* __restrict__ Vth, const u16* __restrict__ Vtl,
    float* __restrict__ OP, float* __restrict__ ML)
{
  __shared__ __align__(16) u16 smem[36864];   // 73728 B -> 2 blocks/CU
  u16* sQh = smem;          // 64 x 72
  u16* sQl = smem + 4608;
  u16* sKh = smem + 9216;
  u16* sKl = smem + 13824;
  u16* sVh = smem + 18432;
  u16* sVl = smem + 23040;
  u16* sPh = smem + 27648;
  u16* sPl = smem + 32256;

  const int bx = blockIdx.x;
  const int half = bx & 1;
  const int qt = (bx >> 1) & 7;
  const int bh = bx >> 4;
  const int b = bh >> 2, h = bh & 3;
  const int t = threadIdx.x;
  const int w = t >> 6, lane = t & 63;
  const int lm = lane & 15, kg = lane >> 4;
  const int qrow0 = b * 512 + qt * 64;

  #pragma unroll
  for (int i = 0; i < 2; i++) {
    const int s = t + i * 256;
    const int r = s >> 3, d = (s & 7) * 8;
    *(short8*)&sQh[r * 72 + d] = *(const short8*)&Qh[(size_t)(qrow0 + r) * 256 + h * 64 + d];
    *(short8*)&sQl[r * 72 + d] = *(const short8*)&Ql[(size_t)(qrow0 + r) * 256 + h * 64 + d];
  }

  float m_i[4], l_i[4];
  floatx4 o_acc[4];
  #pragma unroll
  for (int r = 0; r < 4; r++) { m_i[r] = -INFINITY; l_i[r] = 0.0f; }
  #pragma unroll
  for (int dj = 0; dj < 4; dj++) o_acc[dj] = (floatx4){0.f, 0.f, 0.f, 0.f};

  __syncthreads();
  short8 q_h[2], q_l[2];
  #pragma unroll
  for (int ks = 0; ks < 2; ks++) {
    const int off = (w * 16 + lm) * 72 + ks * 32 + kg * 8;
    q_h[ks] = *(const short8*)&sQh[off];
    q_l[ks] = *(const short8*)&sQl[off];
  }

  for (int ktl = 0; ktl < 4; ktl++) {
    const int kt = half * 4 + ktl;
    __syncthreads();
    {
      const int krow0 = b * 512 + kt * 64;
      #pragma unroll
      for (int i = 0; i < 2; i++) {
        const int s = t + i * 256;
        const int r = s >> 3, d = (s & 7) * 8;
        *(short8*)&sKh[r * 72 + d] = *(const short8*)&Kh[(size_t)(krow0 + r) * 256 + h * 64 + d];
        *(short8*)&sKl[r * 72 + d] = *(const short8*)&Kl[(size_t)(krow0 + r) * 256 + h * 64 + d];
        *(short8*)&sVh[r * 72 + d] = *(const short8*)&Vth[(size_t)(h * 64 + r) * 4096 + krow0 + d];
        *(short8*)&sVl[r * 72 + d] = *(const short8*)&Vtl[(size_t)(h * 64 + r) * 4096 + krow0 + d];
      }
    }
    __syncthreads();

    floatx4 sacc[4];
    #pragma unroll
    for (int nj = 0; nj < 4; nj++) sacc[nj] = (floatx4){0.f, 0.f, 0.f, 0.f};
    #pragma unroll
    for (int ks = 0; ks < 2; ks++) {
      #pragma unroll
      for (int nj = 0; nj < 4; nj++) {
        const int off = (nj * 16 + lm) * 72 + ks * 32 + kg * 8;
        const short8 kb_h = *(const short8*)&sKh[off];
        const short8 kb_l = *(const short8*)&sKl[off];
        sacc[nj] = __builtin_amdgcn_mfma_f32_16x16x32_bf16(q_h[ks], kb_h, sacc[nj], 0, 0, 0);
        sacc[nj] = __builtin_amdgcn_mfma_f32_16x16x32_bf16(q_h[ks], kb_l, sacc[nj], 0, 0, 0);
        sacc[nj] = __builtin_amdgcn_mfma_f32_16x16x32_bf16(q_l[ks], kb_h, sacc[nj], 0, 0, 0);
      }
    }

    float pp[4][4];
    #pragma unroll
    for (int r = 0; r < 4; r++) {
      float mx = -INFINITY;
      #pragma unroll
      for (int nj = 0; nj < 4; nj++) {
        sacc[nj][r] *= 0.125f;
        mx = fmaxf(mx, sacc[nj][r]);
      }
      #pragma unroll
      for (int off = 1; off < 16; off <<= 1) mx = fmaxf(mx, __shfl_xor(mx, off));
      const float mnew = fmaxf(m_i[r], mx);
      const float alpha = expf(m_i[r] - mnew);
      m_i[r] = mnew;
      float rs = 0.0f;
      #pragma unroll
      for (int nj = 0; nj < 4; nj++) { pp[nj][r] = expf(sacc[nj][r] - mnew); rs += pp[nj][r]; }
      #pragma unroll
      for (int off = 1; off < 16; off <<= 1) rs += __shfl_xor(rs, off);
      l_i[r] = l_i[r] * alpha + rs;
      #pragma unroll
      for (int dj = 0; dj < 4; dj++) o_acc[dj][r] *= alpha;
    }

    #pragma unroll
    for (int nj = 0; nj < 4; nj++)
      #pragma unroll
      for (int r = 0; r < 4; r++) {
        u16 ph, pl; split_bf16(pp[nj][r], ph, pl);
        sPh[(w * 16 + kg * 4 + r) * 72 + nj * 16 + lm] = ph;
        sPl[(w * 16 + kg * 4 + r) * 72 + nj * 16 + lm] = pl;
      }

    #pragma unroll
    for (int ks = 0; ks < 2; ks++) {
      const short8 p_h = *(const short8*)&sPh[(w * 16 + lm) * 72 + ks * 32 + kg * 8];
      const short8 p_l = *(const short8*)&sPl[(w * 16 + lm) * 72 + ks * 32 + kg * 8];
      #pragma unroll
      for (int dj = 0; dj < 4; dj++) {
        const int off = (dj * 16 + lm) * 72 + ks * 32 + kg * 8;
        const short8 v_h = *(const short8*)&sVh[off];
        const short8 v_l = *(const short8*)&sVl[off];
        o_acc[dj] = __builtin_amdgcn_mfma_f32_16x16x32_bf16(p_h, v_h, o_acc[dj], 0, 0, 0);
        o_acc[dj] = __builtin_amdgcn_mfma_f32_16x16x32_bf16(p_l, v_h, o_acc[dj], 0, 0, 0);
        o_acc[dj] = __builtin_amdgcn_mfma_f32_16x16x32_bf16(p_h, v_l, o_acc[dj], 0, 0, 0);
      }
    }
  }

  #pragma unroll
  for (int r = 0; r < 4; r++) {
    const int row = w * 16 + kg * 4 + r;
    const int grow = qrow0 + row;
    if (lm == 0) {
      ML[half * 32768 + grow * 8 + h * 2]     = m_i[r];
      ML[half * 32768 + grow * 8 + h * 2 + 1] = l_i[r];
    }
    #pragma unroll
    for (int dj = 0; dj < 4; dj++)
      OP[(size_t)half * 1048576 + (size_t)grow * 256 + h * 64 + dj * 16 + lm] = o_acc[dj][r];
  }
}

// ---------------------------------------------------------------------------
// K3M: merge the two flash partials into normalized bf16 O.
// 1024 blocks x 256 thr, one float4 (4 cols) per thread — fully parallel.
// ---------------------------------------------------------------------------
__global__ __launch_bounds__(256) void k3_merge(
    const float* __restrict__ OP, const float* __restrict__ ML,
    u16* __restrict__ Oh, u16* __restrict__ Ol)
{
  const int tid = blockIdx.x * 256 + threadIdx.x;   // 0..262143
  const int row = tid >> 6;                         // 0..4095
  const int c4 = (tid & 63) * 4;                    // 0..252 step 4
  const int h = c4 >> 6;                            // head
  const float m0v = ML[row * 8 + h * 2],         l0v = ML[row * 8 + h * 2 + 1];
  const float m1v = ML[32768 + row * 8 + h * 2], l1v = ML[32768 + row * 8 + h * 2 + 1];
  const float mn = fmaxf(m0v, m1v);
  const float a0 = expf(m0v - mn), a1 = expf(m1v - mn);
  const float inv = 1.0f / (l0v * a0 + l1v * a1);
  const float4 v0 = *(const float4*)&OP[(size_t)row * 256 + c4];
  const float4 v1 = *(const float4*)&OP[1048576 + (size_t)row * 256 + c4];
  const float mv[4] = {
    (v0.x * a0 + v1.x * a1) * inv, (v0.y * a0 + v1.y * a1) * inv,
    (v0.z * a0 + v1.z * a1) * inv, (v0.w * a0 + v1.w * a1) * inv };
  u64 hp = 0, lp = 0;
  #pragma unroll
  for (int i = 0; i < 4; i++) {
    u16 hx, lx; split_bf16(mv[i], hx, lx);
    hp |= ((u64)hx) << (16 * i);
    lp |= ((u64)lx) << (16 * i);
  }
  *(u64*)&Oh[(size_t)row * 256 + c4] = hp;
  *(u64*)&Ol[(size_t)row * 256 + c4] = lp;
}

// ---------------------------------------------------------------------------
// K4: post-attention tail per 16-row tile. 1024 threads, split-K-4.
// Staging reverted to round-3 form: reads merged bf16 Oh/Ol.
// ---------------------------------------------------------------------------
__global__ __launch_bounds__(1024) void k4_tail(
    const u16* __restrict__ Wh, const u16* __restrict__ Wl,
    const u16* __restrict__ Oh, const u16* __restrict__ Ol,
    const float* __restrict__ SPATIAL32,
    const float* __restrict__ ao_b, const float* __restrict__ n1_g, const float* __restrict__ n1_b,
    const float* __restrict__ f1_b, const float* __restrict__ f2_b,
    const float* __restrict__ n2_g, const float* __restrict__ n2_b,
    const float* __restrict__ op_b, float* __restrict__ OUT)
{
  __shared__ __align__(16) u16 smem[25088];   // buf1 2x4224 (O/X1/X2) + buf2 2x8320 (F)
  __shared__ float redbuf[128];
  __shared__ float PART[3 * 16 * 260];        // split-K partials (row stride 260)
  u16* B1h = smem;             // 16 x 264
  u16* B1l = smem + 4224;
  u16* Fh  = smem + 8448;      // 16 x 520
  u16* Fl  = smem + 16768;

  const int t = threadIdx.x;
  const int w = t >> 6, lane = t & 63;
  const int ww = w & 3, set = w >> 2;
  const int lm = lane & 15, kg = lane >> 4;
  const int m0 = blockIdx.x * 16;

  // ---- stage O tile (512 threads, one pass) ----
  {
    const u16* Gh = Oh + (size_t)m0 * 256;
    const u16* Gl = Ol + (size_t)m0 * 256;
    if (t < 512) {
      const int row = t >> 5, c = (t & 31) * 8;
      *(short8*)&B1h[row * 264 + c] = *(const short8*)&Gh[(size_t)row * 256 + c];
      *(short8*)&B1l[row * 264 + c] = *(const short8*)&Gl[(size_t)row * 256 + c];
    }
    __syncthreads();
  }

  // ---- step1: X1 = LN(spatial + O @ ao^T + b) ----
  floatx4 acc[4];
  #pragma unroll
  for (int j = 0; j < 4; j++) acc[j] = (floatx4){0.f,0.f,0.f,0.f};
  mm16_ks<4, 256, 4>(B1h, B1l, 264, Wh + W_AO, Wl + W_AO, acc);
  reduce_sets<4>(acc, PART);

  float x1reg[4][4];
  {
    float v[4][4];
    if (set == 0) {
      #pragma unroll
      for (int nj = 0; nj < 4; nj++) {
        const int col = ww * 64 + nj * 16 + lm;
        #pragma unroll
        for (int r = 0; r < 4; r++)
          v[nj][r] = acc[nj][r] + ao_b[col] + SPATIAL32[(size_t)(m0 + kg * 4 + r) * 256 + col];
      }
    } else {
      #pragma unroll
      for (int nj = 0; nj < 4; nj++)
        #pragma unroll
        for (int r = 0; r < 4; r++) v[nj][r] = 0.0f;
    }
    float mean[4], rstd[4];
    ln_rows16<256, 4>(v, redbuf, redbuf + 64, mean, rstd);
    if (set == 0) {
      #pragma unroll
      for (int nj = 0; nj < 4; nj++) {
        const int col = ww * 64 + nj * 16 + lm;
        #pragma unroll
        for (int r = 0; r < 4; r++) {
          const float y = n1_g[col] * (v[nj][r] - mean[r]) * rstd[r] + n1_b[col];
          x1reg[nj][r] = y;
          u16 h, l; split_bf16(y, h, l);
          B1h[(kg * 4 + r) * 264 + col] = h;   // X1 overwrites O
          B1l[(kg * 4 + r) * 264 + col] = l;
        }
      }
    }
  }
  __syncthreads();

  // ---- step2: F1 = gelu(X1 @ f1^T + b), two 256-col passes ----
  #pragma unroll
  for (int ct = 0; ct < 2; ct++) {
    floatx4 a4[4];
    #pragma unroll
    for (int j = 0; j < 4; j++) a4[j] = (floatx4){0.f,0.f,0.f,0.f};
    mm16_ks<4, 256, 4>(B1h, B1l, 264,
                       Wh + W_F1 + (size_t)ct * 65536, Wl + W_F1 + (size_t)ct * 65536, a4);
    reduce_sets<4>(a4, PART);
    if (set == 0) {
      #pragma unroll
      for (int nj = 0; nj < 4; nj++) {
        const int col = ct * 256 + ww * 64 + nj * 16 + lm;
        #pragma unroll
        for (int r = 0; r < 4; r++) {
          const float y = gelu_f(a4[nj][r] + f1_b[col]);
          u16 h, l; split_bf16(y, h, l);
          Fh[(kg * 4 + r) * 520 + col] = h;
          Fl[(kg * 4 + r) * 520 + col] = l;
        }
      }
    }
  }
  __syncthreads();

  // ---- step3: X2 = LN(X1 + F1 @ f2^T + b) ----
  #pragma unroll
  for (int j = 0; j < 4; j++) acc[j] = (floatx4){0.f,0.f,0.f,0.f};
  mm16_ks<4, 512, 4>(Fh, Fl, 520, Wh + W_F2, Wl + W_F2, acc);
  reduce_sets<4>(acc, PART);
  {
    float v[4][4];
    if (set == 0) {
      #pragma unroll
      for (int nj = 0; nj < 4; nj++) {
        const int col = ww * 64 + nj * 16 + lm;
        #pragma unroll
        for (int r = 0; r < 4; r++)
          v[nj][r] = acc[nj][r] + f2_b[col] + x1reg[nj][r];
      }
    } else {
      #pragma unroll
      for (int nj = 0; nj < 4; nj++)
        #pragma unroll
        for (int r = 0; r < 4; r++) v[nj][r] = 0.0f;
    }
    float mean[4], rstd[4];
    ln_rows16<256, 4>(v, redbuf, redbuf + 64, mean, rstd);
    if (set == 0) {
      #pragma unroll
      for (int nj = 0; nj < 4; nj++) {
        const int col = ww * 64 + nj * 16 + lm;
        #pragma unroll
        for (int r = 0; r < 4; r++) {
          const float y = n2_g[col] * (v[nj][r] - mean[r]) * rstd[r] + n2_b[col];
          u16 h, l; split_bf16(y, h, l);
          B1h[(kg * 4 + r) * 264 + col] = h;   // X2 overwrites X1
          B1l[(kg * 4 + r) * 264 + col] = l;
        }
      }
    }
  }
  __syncthreads();

  // ---- step4: OUT = X2 @ op^T + b ----
  #pragma unroll
  for (int j = 0; j < 4; j++) acc[j] = (floatx4){0.f,0.f,0.f,0.f};
  mm16_ks<4, 256, 4>(B1h, B1l, 264, Wh + W_OP, Wl + W_OP, acc);
  reduce_sets<4>(acc, PART);
  if (set == 0) {
    #pragma unroll
    for (int nj = 0; nj < 4; nj++) {
      const int col = ww * 64 + nj * 16 + lm;
      #pragma unroll
      for (int r = 0; r < 4; r++)
        OUT[(size_t)(m0 + kg * 4 + r) * 256 + col] = acc[nj][r] + op_b[col];
    }
  }
}

// ---------------------------------------------------------------------------
extern "C" void kernel_launch(void* const* d_in, const int* in_sizes, int n_in,
                              void* d_out, int out_size, void* d_ws, size_t ws_size,
                              hipStream_t stream) {
  const float* image   = (const float*)d_in[0];
  const float* coords  = (const float*)d_in[1];
  const int*   labels  = (const int*)d_in[2];
  const float* pe_w    = (const float*)d_in[3];
  const float* pe_b    = (const float*)d_in[4];
  const float* temb    = (const float*)d_in[5];
  const float* fbi     = (const float*)d_in[6];
  const float* fe1_w   = (const float*)d_in[7];
  const float* fe1_b   = (const float*)d_in[8];
  const float* feln1_g = (const float*)d_in[9];
  const float* feln1_b = (const float*)d_in[10];
  const float* fe2_w   = (const float*)d_in[11];
  const float* fe2_b   = (const float*)d_in[12];
  const float* feln2_g = (const float*)d_in[13];
  const float* feln2_b = (const float*)d_in[14];
  const float* in_w    = (const float*)d_in[15];
  const float* in_b    = (const float*)d_in[16];
  const float* ao_w    = (const float*)d_in[17];
  const float* ao_b    = (const float*)d_in[18];
  const float* n1_g    = (const float*)d_in[19];
  const float* n1_b    = (const float*)d_in[20];
  const float* f1_w    = (const float*)d_in[21];
  const float* f1_b    = (const float*)d_in[22];
  const float* f2_w    = (const float*)d_in[23];
  const float* f2_b    = (const float*)d_in[24];
  const float* n2_g    = (const float*)d_in[25];
  const float* n2_b    = (const float*)d_in[26];
  const float* op_w    = (const float*)d_in[27];
  const float* op_b    = (const float*)d_in[28];

  float* ws = (float*)d_ws;
  float* SPATIAL32 = ws;                       // 1M floats
  u16* S = (u16*)(ws + 2 * (1u << 20));
  u16* Wh = S;
  u16* Wl = S + 690176;
  u16* PEh   = S + 1380352;  u16* PEl   = PEh + 1048576;
  u16* FEATh = S + 3477504;  u16* FEATl = FEATh + 65536;
  u16* FQh   = S + 4657152;  u16* FQl   = FQh + 1048576;
  u16* SPh   = S + 6754304;  u16* SPl   = SPh + 1048576;
  u16* Qh    = S + 8851456;  u16* Ql    = Qh + 1048576;
  u16* Kh    = S + 10948608; u16* Kl    = Kh + 1048576;
  u16* Vth   = S + 13045760; u16* Vtl   = Vth + 1048576;
  float* OP  = (float*)(S + 15142912);   // 2 x 4096x256 f32 partial O (4 Mu16)
  float* ML  = (float*)(S + 19337216);   // 2 x 4096x8 f32 (m,l)       (128 Ku16)
  u16* Oh    = S + 19468288; u16* Ol = Oh + 1048576;

  float* OUT = (float*)d_out;

  k0_prep<<<6792, 64, 0, stream>>>(
      image, coords, fbi, pe_w, fe1_w, fe2_w, in_w, ao_w, f1_w, f2_w, op_w,
      Wh, Wl, PEh, PEl, FEATh, FEATl);
  k1_front<<<512, 256, 0, stream>>>(
      Wh, Wl, PEh, PEl, FEATh, FEATl, pe_b, labels, temb,
      fe1_b, feln1_g, feln1_b, fe2_b, feln2_g, feln2_b,
      SPATIAL32, SPh, SPl, FQh, FQl);
  k2_qkv<<<768, 512, 0, stream>>>(
      Wh, Wl, SPh, SPl, FQh, FQl, in_b, Qh, Ql, Kh, Kl, Vth, Vtl);
  k3_attn<<<512, 256, 0, stream>>>(Qh, Ql, Kh, Kl, Vth, Vtl, OP, ML);
  k3_merge<<<1024, 256, 0, stream>>>(OP, ML, Oh, Ol);
  k4_tail<<<256, 1024, 0, stream>>>(
      Wh, Wl, Oh, Ol, SPATIAL32, ao_b, n1_g, n1_b, f1_b, f2_b, n2_g, n2_b, op_b, OUT);
}